// Round 1
// baseline (4862.629 us; speedup 1.0000x reference)
//
#include <hip/hip_runtime.h>
#include <hip/hip_bf16.h>

#define B_ 8
#define N_ 1025
#define C_ 1024
#define H_ 8
#define D_ 128
#define TOK_ 1024
#define LORA_ 16
#define M_ (B_*N_)   // 8200

// ---------------- tokens: TkT[c][t] = sum_l a[t,l]*b[l,c] (pre-transposed) ------------
__global__ __launch_bounds__(256) void tokens_kernel(
    const float* __restrict__ ak, const float* __restrict__ bk,
    const float* __restrict__ av, const float* __restrict__ bv,
    float* __restrict__ TkT, float* __restrict__ TvT)
{
    const float* a = blockIdx.z ? av : ak;
    const float* b = blockIdx.z ? bv : bk;
    float* o = blockIdx.z ? TvT : TkT;
    int t = blockIdx.x * 256 + threadIdx.x;
    int c = blockIdx.y;
    float s = 0.f;
#pragma unroll
    for (int l = 0; l < LORA_; ++l) s += a[t * LORA_ + l] * b[l * C_ + c];
    o[(size_t)c * TOK_ + t] = s;
}

// ---------------- SE module: weighted_cls[b,c] = x[b,0,c]*sigmoid(relu(x[b,1:,c]^T W1 + b1) W2 + b2)
__global__ __launch_bounds__(256) void se_kernel(
    const float* __restrict__ x, const float* __restrict__ W1,
    const float* __restrict__ b1, const float* __restrict__ W2,
    const float* __restrict__ b2, float* __restrict__ wcls)
{
    __shared__ float xs[1024][8];     // [t][cc]
    __shared__ float red[8][257];
    const int tid = threadIdx.x;
    const int b  = blockIdx.x >> 7;          // / 128
    const int c0 = (blockIdx.x & 127) * 8;
    const float* xb = x + (size_t)b * N_ * C_;
    for (int i = tid; i < 1024 * 8; i += 256) {
        int t = i >> 3, cc = i & 7;
        xs[t][cc] = xb[(size_t)(1 + t) * C_ + c0 + cc];
    }
    __syncthreads();
    float acc[8] = {0.f,0.f,0.f,0.f,0.f,0.f,0.f,0.f};
    const int j = tid;    // 256 output features
    for (int t = 0; t < 1024; ++t) {
        float w = W1[t * 256 + j];
        const float4* xr = (const float4*)&xs[t][0];
        float4 x0 = xr[0], x1 = xr[1];
        acc[0] += x0.x * w; acc[1] += x0.y * w; acc[2] += x0.z * w; acc[3] += x0.w * w;
        acc[4] += x1.x * w; acc[5] += x1.y * w; acc[6] += x1.z * w; acc[7] += x1.w * w;
    }
    float w2 = W2[j];
#pragma unroll
    for (int cc = 0; cc < 8; ++cc) {
        float h = acc[cc] + b1[j];
        h = h > 0.f ? h : 0.f;
        red[cc][j] = h * w2;
    }
    __syncthreads();
    if (tid < 8) {
        float s = 0.f;
        for (int jj = 0; jj < 256; ++jj) s += red[tid][jj];
        float aw = 1.f / (1.f + expf(-(s + b2[0])));
        wcls[b * C_ + c0 + tid] = xb[c0 + tid] * aw;
    }
}

// ---------------- generic fp32 tiled GEMM: C = A1@B1 (+ A2@B2) (+bias) (+cls add) -----
// A row-major (M,1024); B row-major (1024, ldb) with column window baked into pointer;
// C row-major (M,1024).
template<int DUAL, int BIAS, int CLS>
__global__ __launch_bounds__(256) void gemm_f32(
    const float* __restrict__ A1, const float* __restrict__ B1, int ldb1,
    const float* __restrict__ A2, const float* __restrict__ B2, int ldb2,
    const float* __restrict__ bias, const float* __restrict__ wcls,
    float* __restrict__ Cc, int M)
{
    __shared__ float As[16][65];   // [k][m], padded
    __shared__ float Bs[16][65];   // [k][n]
    const int tid = threadIdx.x;
    const int row0 = blockIdx.x * 64, col0 = blockIdx.y * 64;
    const int r0 = (tid >> 4) * 4, c0 = (tid & 15) * 4;
    float acc[4][4] = {};

    for (int pass = 0; pass < 1 + DUAL; ++pass) {
        const float* A = pass ? A2 : A1;
        const float* B = pass ? B2 : B1;
        const int ldb = pass ? ldb2 : ldb1;
        for (int k0 = 0; k0 < 1024; k0 += 16) {
            for (int i = tid; i < 1024; i += 256) {
                int m = i >> 4, kk = i & 15;
                int gr = row0 + m;
                As[kk][m] = (gr < M) ? A[(size_t)gr * 1024 + k0 + kk] : 0.f;
            }
            for (int i = tid; i < 1024; i += 256) {
                int kk = i >> 6, c = i & 63;
                Bs[kk][c] = B[(size_t)(k0 + kk) * ldb + col0 + c];
            }
            __syncthreads();
#pragma unroll
            for (int kk = 0; kk < 16; ++kk) {
                float a0 = As[kk][r0],     a1 = As[kk][r0 + 1];
                float a2 = As[kk][r0 + 2], a3 = As[kk][r0 + 3];
                float b0 = Bs[kk][c0],     b1v = Bs[kk][c0 + 1];
                float b2v = Bs[kk][c0 + 2], b3 = Bs[kk][c0 + 3];
                acc[0][0] += a0 * b0; acc[0][1] += a0 * b1v; acc[0][2] += a0 * b2v; acc[0][3] += a0 * b3;
                acc[1][0] += a1 * b0; acc[1][1] += a1 * b1v; acc[1][2] += a1 * b2v; acc[1][3] += a1 * b3;
                acc[2][0] += a2 * b0; acc[2][1] += a2 * b1v; acc[2][2] += a2 * b2v; acc[2][3] += a2 * b3;
                acc[3][0] += a3 * b0; acc[3][1] += a3 * b1v; acc[3][2] += a3 * b2v; acc[3][3] += a3 * b3;
            }
            __syncthreads();
        }
    }
#pragma unroll
    for (int i = 0; i < 4; ++i) {
        int gr = row0 + r0 + i;
        if (gr >= M) continue;
#pragma unroll
        for (int jj = 0; jj < 4; ++jj) {
            int gc = col0 + c0 + jj;
            float v = acc[i][jj];
            if (BIAS) v += bias[gc];
            if (CLS) { if (gr % N_ == 0) v += wcls[(gr / N_) * C_ + gc]; }
            Cc[(size_t)gr * 1024 + gc] = v;
        }
    }
}

// ---------------- attention: per-block (b, h, 8 q-rows), full-row softmax in LDS ------
__global__ __launch_bounds__(256) void attn_kernel(
    const float* __restrict__ q, const float* __restrict__ kk,
    const float* __restrict__ vv, float* __restrict__ out)
{
    __shared__ float qs[8][128];
    __shared__ float ss[8][1025];
    __shared__ float lrow[8];
    __shared__ float part[8][128];
    const int tid = threadIdx.x;
    const int n0 = blockIdx.x * 8;
    const int b = blockIdx.y >> 3, h = blockIdx.y & 7;
    const size_t base = (size_t)b * N_ * C_ + h * D_;

    for (int i = tid; i < 8 * 128; i += 256) {
        int r = i >> 7, d = i & 127;
        int n = n0 + r;
        qs[r][d] = (n < N_) ? q[base + (size_t)n * C_ + d] : 0.f;
    }
    __syncthreads();

    const float scale = 0.08838834764831845f;   // 1/sqrt(128)
    for (int j = tid; j < N_; j += 256) {
        float acc[8] = {};
        const float4* kr = (const float4*)(kk + base + (size_t)j * C_);
#pragma unroll 8
        for (int dc = 0; dc < 32; ++dc) {
            float4 kv = kr[dc];
#pragma unroll
            for (int r = 0; r < 8; ++r) {
                acc[r] += kv.x * qs[r][dc * 4] + kv.y * qs[r][dc * 4 + 1]
                        + kv.z * qs[r][dc * 4 + 2] + kv.w * qs[r][dc * 4 + 3];
            }
        }
#pragma unroll
        for (int r = 0; r < 8; ++r) ss[r][j] = acc[r] * scale;
    }
    __syncthreads();

    {   // softmax: 8 groups of 32 lanes, one row each
        const int rw = tid >> 5, l = tid & 31;
        float m = -1e30f;
        for (int j = l; j < N_; j += 32) m = fmaxf(m, ss[rw][j]);
        for (int off = 16; off >= 1; off >>= 1) m = fmaxf(m, __shfl_xor(m, off));
        float s = 0.f;
        for (int j = l; j < N_; j += 32) { float p = expf(ss[rw][j] - m); ss[rw][j] = p; s += p; }
        for (int off = 16; off >= 1; off >>= 1) s += __shfl_xor(s, off);
        if (l == 0) lrow[rw] = s;
    }
    __syncthreads();

    const int d = tid & 127, g = tid >> 7;
    float accp[8] = {};
    for (int j = g; j < N_; j += 2) {
        float v = vv[base + (size_t)j * C_ + d];
#pragma unroll
        for (int r = 0; r < 8; ++r) accp[r] += ss[r][j] * v;
    }
    if (g == 1) {
#pragma unroll
        for (int r = 0; r < 8; ++r) part[r][d] = accp[r];
    }
    __syncthreads();
    if (g == 0) {
#pragma unroll
        for (int r = 0; r < 8; ++r) {
            int n = n0 + r;
            if (n < N_) out[base + (size_t)n * C_ + d] = (accp[r] + part[r][d]) / lrow[r];
        }
    }
}

extern "C" void kernel_launch(void* const* d_in, const int* in_sizes, int n_in,
                              void* d_out, int out_size, void* d_ws, size_t ws_size,
                              hipStream_t stream)
{
    const float* x       = (const float*)d_in[0];
    const float* style_k = (const float*)d_in[1];
    const float* style_v = (const float*)d_in[2];
    const float* W_qkv   = (const float*)d_in[3];
    const float* W_proj  = (const float*)d_in[4];
    const float* b_proj  = (const float*)d_in[5];
    const float* ak      = (const float*)d_in[6];
    const float* bk      = (const float*)d_in[7];
    const float* av      = (const float*)d_in[8];
    const float* bv      = (const float*)d_in[9];
    const float* W1      = (const float*)d_in[10];
    const float* b1      = (const float*)d_in[11];
    const float* W2      = (const float*)d_in[12];
    const float* b2      = (const float*)d_in[13];

    float* outp   = (float*)d_out;
    float* vv_out = outp + (size_t)B_ * N_ * C_;   // second tuple element lives in d_out

    float* ws    = (float*)d_ws;
    float* TkT   = ws;                                  // 1M floats
    float* TvT   = TkT + (size_t)TOK_ * C_;             // 1M
    float* wcls  = TvT + (size_t)TOK_ * C_;             // 8K
    float* qbuf  = wcls + B_ * C_;                      // 8.4M (reused as attn_out)
    float* kkbuf = qbuf + (size_t)B_ * N_ * C_;         // 8.4M

    tokens_kernel<<<dim3(TOK_ / 256, C_, 2), 256, 0, stream>>>(ak, bk, av, bv, TkT, TvT);
    se_kernel<<<dim3(B_ * (C_ / 8)), 256, 0, stream>>>(x, W1, b1, W2, b2, wcls);

    dim3 gg((M_ + 63) / 64, C_ / 64);
    gemm_f32<0,0,0><<<gg, 256, 0, stream>>>(x, W_qkv,          3 * C_, nullptr,  nullptr, 0,
                                            nullptr, nullptr, qbuf,   M_);
    gemm_f32<1,0,0><<<gg, 256, 0, stream>>>(x, W_qkv + C_,     3 * C_, style_k,  TkT,     TOK_,
                                            nullptr, nullptr, kkbuf,  M_);
    gemm_f32<1,0,0><<<gg, 256, 0, stream>>>(x, W_qkv + 2 * C_, 3 * C_, style_v,  TvT,     TOK_,
                                            nullptr, nullptr, vv_out, M_);

    attn_kernel<<<dim3((N_ + 7) / 8, B_ * H_), 256, 0, stream>>>(qbuf, kkbuf, vv_out, qbuf);

    gemm_f32<0,1,1><<<gg, 256, 0, stream>>>(qbuf, W_proj, C_, nullptr, nullptr, 0,
                                            b_proj, wcls, outp, M_);
}

// Round 2
// 580.134 us; speedup vs baseline: 8.3819x; 8.3819x over previous
//
#include <hip/hip_runtime.h>
#include <hip/hip_bf16.h>
#include <stdint.h>

#define B_ 8
#define N_ 1025
#define C_ 1024
#define H_ 8
#define D_ 128
#define TOK_ 1024
#define LORA_ 16
#define M_ 8200          // B_*N_
#define NPAD_ 1032       // padded N for vvT (16B-aligned rows)

using bf16x8 = __attribute__((ext_vector_type(8))) short;
using f32x4  = __attribute__((ext_vector_type(4))) float;
typedef unsigned short u16;

__device__ __forceinline__ u16 f2bf(float f) {
    union { float f; unsigned u; } v; v.f = f;
    unsigned r = v.u + 0x7fffu + ((v.u >> 16) & 1u);   // RNE
    return (u16)(r >> 16);
}

__device__ __forceinline__ void gload16(const u16* g, u16* l) {
    __builtin_amdgcn_global_load_lds(
        (const __attribute__((address_space(1))) void*)g,
        (__attribute__((address_space(3))) void*)l, 16, 0, 0);
}

// ---------------- tokens: Tk[t][c] = sum_l ak[t,l]*bk[l,c]  (bf16, row-major = B^T for lora GEMM)
__global__ __launch_bounds__(256) void tokens_kernel(
    const float* __restrict__ ak, const float* __restrict__ bk,
    const float* __restrict__ av, const float* __restrict__ bv,
    u16* __restrict__ Tk, u16* __restrict__ Tv)
{
    const float* a = blockIdx.z ? av : ak;
    const float* b = blockIdx.z ? bv : bk;
    u16* o = blockIdx.z ? Tv : Tk;
    int c = blockIdx.x * 256 + threadIdx.x;
    int t = blockIdx.y;
    float s = 0.f;
#pragma unroll
    for (int l = 0; l < LORA_; ++l) s += a[t * LORA_ + l] * b[l * C_ + c];
    o[(size_t)t * C_ + c] = f2bf(s);
}

// ---------------- weight transpose+cast: in (K x Nw) f32 -> out (Nw x K) bf16 ----------
__global__ __launch_bounds__(256) void wt_kernel(
    const float* __restrict__ in, u16* __restrict__ out, int K, int Nw)
{
    __shared__ float t[32][33];
    int n0 = blockIdx.x * 32, k0 = blockIdx.y * 32;
    int tx = threadIdx.x & 31, ty = threadIdx.x >> 5;
#pragma unroll
    for (int yy = 0; yy < 32; yy += 8)
        t[ty + yy][tx] = in[(size_t)(k0 + ty + yy) * Nw + n0 + tx];
    __syncthreads();
#pragma unroll
    for (int yy = 0; yy < 32; yy += 8)
        out[(size_t)(n0 + ty + yy) * K + k0 + tx] = f2bf(t[tx][ty + yy]);
}

// ---------------- vv (f32, [b*1025+n][h*128+d]) -> vvT bf16 [bh*128+d][NPAD_] ----------
__global__ __launch_bounds__(256) void vvt_kernel(
    const float* __restrict__ vv, u16* __restrict__ vvT)
{
    __shared__ float t[32][33];
    int n0 = blockIdx.x * 32, d0 = blockIdx.y * 32, bh = blockIdx.z;
    int b = bh >> 3, h = bh & 7;
    int tx = threadIdx.x & 31, ty = threadIdx.x >> 5;
#pragma unroll
    for (int yy = 0; yy < 32; yy += 8) {
        int n = n0 + ty + yy; if (n > 1024) n = 1024;
        t[ty + yy][tx] = vv[((size_t)(b * N_) + n) * C_ + h * D_ + d0 + tx];
    }
    __syncthreads();
#pragma unroll
    for (int yy = 0; yy < 32; yy += 8) {
        int n = n0 + tx;
        if (n < NPAD_)
            vvT[((size_t)bh * D_ + d0 + ty + yy) * NPAD_ + n] = f2bf(t[tx][ty + yy]);
    }
}

// ---------------- SE module (unchanged fp32) -------------------------------------------
__global__ __launch_bounds__(256) void se_kernel(
    const float* __restrict__ x, const float* __restrict__ W1,
    const float* __restrict__ b1, const float* __restrict__ W2,
    const float* __restrict__ b2, float* __restrict__ wcls)
{
    __shared__ float xs[1024][8];
    __shared__ float red[8][257];
    const int tid = threadIdx.x;
    const int b  = blockIdx.x >> 7;
    const int c0 = (blockIdx.x & 127) * 8;
    const float* xb = x + (size_t)b * N_ * C_;
    for (int i = tid; i < 1024 * 8; i += 256) {
        int t = i >> 3, cc = i & 7;
        xs[t][cc] = xb[(size_t)(1 + t) * C_ + c0 + cc];
    }
    __syncthreads();
    float acc[8] = {};
    const int j = tid;
    for (int t = 0; t < 1024; ++t) {
        float w = W1[t * 256 + j];
        const float4* xr = (const float4*)&xs[t][0];
        float4 x0 = xr[0], x1 = xr[1];
        acc[0] += x0.x * w; acc[1] += x0.y * w; acc[2] += x0.z * w; acc[3] += x0.w * w;
        acc[4] += x1.x * w; acc[5] += x1.y * w; acc[6] += x1.z * w; acc[7] += x1.w * w;
    }
    float w2 = W2[j];
#pragma unroll
    for (int cc = 0; cc < 8; ++cc) {
        float h = acc[cc] + b1[j];
        h = h > 0.f ? h : 0.f;
        red[cc][j] = h * w2;
    }
    __syncthreads();
    if (tid < 8) {
        float s = 0.f;
        for (int jj = 0; jj < 256; ++jj) s += red[tid][jj];
        float aw = 1.f / (1.f + expf(-(s + b2[0])));
        wcls[b * C_ + c0 + tid] = xb[c0 + tid] * aw;
    }
}

// ---------------- bf16 MFMA GEMM core: one 1024-K pass into acc ------------------------
// A: row-major (M_ x 1024), f32 (converted) or bf16. Bt: B^T row-major (ncols x 1024) bf16.
// 128x128 tile, BK=64, 4 waves in 2x2, each wave 4x4 16x16 frags. XOR-swizzled LDS.
template<bool AF32>
__device__ __forceinline__ void gemm_pass(
    const void* Ap, const u16* Bt, int row0, int nb0,
    u16* As, u16* Bs, f32x4 acc[4][4],
    const int tid, const int lane, const int wid, const int wr, const int wc)
{
    for (int k0 = 0; k0 < 1024; k0 += 64) {
        __syncthreads();
        // stage A (reg-staged; fp32->bf16 on the fly)
#pragma unroll
        for (int cw = 0; cw < 4; ++cw) {
            int c = tid + cw * 256;
            int row = c >> 3, kc = (c & 7) * 8;
            int grow = row0 + row; if (grow > M_ - 1) grow = M_ - 1;
            bf16x8 v;
            if (AF32) {
                const float* g = (const float*)Ap + (size_t)grow * 1024 + k0 + kc;
                float4 f0 = *(const float4*)g;
                float4 f1 = *(const float4*)(g + 4);
                v[0] = (short)f2bf(f0.x); v[1] = (short)f2bf(f0.y);
                v[2] = (short)f2bf(f0.z); v[3] = (short)f2bf(f0.w);
                v[4] = (short)f2bf(f1.x); v[5] = (short)f2bf(f1.y);
                v[6] = (short)f2bf(f1.z); v[7] = (short)f2bf(f1.w);
            } else {
                v = *(const bf16x8*)((const u16*)Ap + (size_t)grow * 1024 + k0 + kc);
            }
            int byte = (row * 128 + kc * 2) ^ ((row & 7) << 4);
            *(bf16x8*)((char*)As + byte) = v;
        }
        // stage B via global_load_lds, source pre-swizzled (rule #21)
#pragma unroll
        for (int j = 0; j < 4; ++j) {
            int i = wid * 4 + j;
            int p = i * 1024 + 16 * lane;
            int row = p >> 7, cb = p & 127;
            int cbs = cb ^ ((row & 7) << 4);
            gload16(Bt + (size_t)(nb0 + row) * 1024 + k0 + (cbs >> 1), Bs + i * 512);
        }
        __syncthreads();
        // compute
#pragma unroll
        for (int ks = 0; ks < 2; ++ks) {
            bf16x8 af[4], bfr[4];
#pragma unroll
            for (int mi = 0; mi < 4; ++mi) {
                int r = wr * 64 + mi * 16 + (lane & 15);
                int byte = (r * 128 + ks * 64 + (lane >> 4) * 16) ^ ((r & 7) << 4);
                af[mi] = *(const bf16x8*)((const char*)As + byte);
            }
#pragma unroll
            for (int ni = 0; ni < 4; ++ni) {
                int r = wc * 64 + ni * 16 + (lane & 15);
                int byte = (r * 128 + ks * 64 + (lane >> 4) * 16) ^ ((r & 7) << 4);
                bfr[ni] = *(const bf16x8*)((const char*)Bs + byte);
            }
#pragma unroll
            for (int mi = 0; mi < 4; ++mi)
#pragma unroll
                for (int ni = 0; ni < 4; ++ni)
                    acc[mi][ni] = __builtin_amdgcn_mfma_f32_16x16x32_bf16(
                        af[mi], bfr[ni], acc[mi][ni], 0, 0, 0);
        }
    }
}

// ---------------- fused qkv GEMM: regions q / kk(+lora) / vv(+lora) --------------------
__global__ __launch_bounds__(256) void qkv_gemm(
    const float* __restrict__ x, const float* __restrict__ sk, const float* __restrict__ sv,
    const u16* __restrict__ WqkvT, const u16* __restrict__ Tk, const u16* __restrict__ Tv,
    u16* __restrict__ qb, u16* __restrict__ kkb, float* __restrict__ vvout)
{
    __shared__ u16 As[8192], Bs[8192];
    const int tid = threadIdx.x, lane = tid & 63, wid = tid >> 6;
    const int wr = wid >> 1, wc = wid & 1;
    const int row0 = blockIdx.x * 128;
    const int ct = blockIdx.y, region = ct >> 3;
    const f32x4 FZ = {0.f, 0.f, 0.f, 0.f};
    f32x4 acc[4][4];
#pragma unroll
    for (int mi = 0; mi < 4; ++mi)
#pragma unroll
        for (int ni = 0; ni < 4; ++ni) acc[mi][ni] = FZ;

    gemm_pass<true>(x, WqkvT, row0, ct * 128, As, Bs, acc, tid, lane, wid, wr, wc);
    if (region == 1) gemm_pass<true>(sk, Tk, row0, (ct & 7) * 128, As, Bs, acc, tid, lane, wid, wr, wc);
    if (region == 2) gemm_pass<true>(sv, Tv, row0, (ct & 7) * 128, As, Bs, acc, tid, lane, wid, wr, wc);

    const int creg = (ct & 7) * 128;
#pragma unroll
    for (int mi = 0; mi < 4; ++mi) {
#pragma unroll
        for (int r = 0; r < 4; ++r) {
            int gr = row0 + wr * 64 + mi * 16 + (lane >> 4) * 4 + r;
            if (gr >= M_) continue;
#pragma unroll
            for (int ni = 0; ni < 4; ++ni) {
                int gc = creg + wc * 64 + ni * 16 + (lane & 15);
                float v = acc[mi][ni][r];
                if (region == 0)      qb [(size_t)gr * C_ + gc] = f2bf(v);
                else if (region == 1) kkb[(size_t)gr * C_ + gc] = f2bf(v);
                else                  vvout[(size_t)gr * C_ + gc] = v;
            }
        }
    }
}

// ---------------- proj GEMM: out = ob @ WprojT^T + b_proj (+wcls on cls rows) ----------
__global__ __launch_bounds__(256) void proj_gemm(
    const u16* __restrict__ ob, const u16* __restrict__ WprojT,
    const float* __restrict__ bias, const float* __restrict__ wcls,
    float* __restrict__ outp)
{
    __shared__ u16 As[8192], Bs[8192];
    const int tid = threadIdx.x, lane = tid & 63, wid = tid >> 6;
    const int wr = wid >> 1, wc = wid & 1;
    const int row0 = blockIdx.x * 128;
    const int ct = blockIdx.y;
    const f32x4 FZ = {0.f, 0.f, 0.f, 0.f};
    f32x4 acc[4][4];
#pragma unroll
    for (int mi = 0; mi < 4; ++mi)
#pragma unroll
        for (int ni = 0; ni < 4; ++ni) acc[mi][ni] = FZ;

    gemm_pass<false>(ob, WprojT, row0, ct * 128, As, Bs, acc, tid, lane, wid, wr, wc);

#pragma unroll
    for (int mi = 0; mi < 4; ++mi) {
#pragma unroll
        for (int r = 0; r < 4; ++r) {
            int gr = row0 + wr * 64 + mi * 16 + (lane >> 4) * 4 + r;
            if (gr >= M_) continue;
#pragma unroll
            for (int ni = 0; ni < 4; ++ni) {
                int gc = ct * 128 + wc * 64 + ni * 16 + (lane & 15);
                float v = acc[mi][ni][r] + bias[gc];
                if (gr % N_ == 0) v += wcls[(gr / N_) * C_ + gc];
                outp[(size_t)gr * C_ + gc] = v;
            }
        }
    }
}

// ---------------- flash attention, bf16 MFMA -------------------------------------------
// block = 4 waves; wave w owns 16 q rows (qt*64 + w*16 ..). KV tiles of 64. Online softmax.
__global__ __launch_bounds__(256) void attn_kernel(
    const u16* __restrict__ qb, const u16* __restrict__ kkb,
    const u16* __restrict__ vvT, u16* __restrict__ ob)
{
    __shared__ u16 Ks[8192];   // [64 kv][128 d], swizzled
    __shared__ u16 Vs[8192];   // [128 d][64 kv], swizzled
    __shared__ u16 Ps[4096];   // per-wave [16 q][64 kv], swizzled
    const int tid = threadIdx.x, lane = tid & 63, wid = tid >> 6;
    const int qt = blockIdx.x, bh = blockIdx.y, b = bh >> 3, h = bh & 7;
    const int n0q = qt * 64;
    const float SCALE = 0.08838834764831845f;

    // Q fragments (A-layout: row = lane&15, k = (lane>>4)*8 + j), row clamped
    bf16x8 qf[4];
    {
        int qrow = n0q + wid * 16 + (lane & 15); if (qrow > 1024) qrow = 1024;
        const u16* qbase = qb + (size_t)(b * N_ + qrow) * C_ + h * D_ + (lane >> 4) * 8;
#pragma unroll
        for (int ks = 0; ks < 4; ++ks) qf[ks] = *(const bf16x8*)(qbase + ks * 32);
    }

    float mrow[4], lsum[4];
    const f32x4 FZ = {0.f, 0.f, 0.f, 0.f};
    f32x4 of[8];
#pragma unroll
    for (int r = 0; r < 4; ++r) { mrow[r] = -3e38f; lsum[r] = 0.f; }
#pragma unroll
    for (int ct = 0; ct < 8; ++ct) of[ct] = FZ;

    char* psb = (char*)Ps + wid * 2048;

    for (int t = 0; t < 17; ++t) {
        const int kv0 = t * 64;
        __syncthreads();
        // stage K tile [64][128] (rows = kv, 256B rows)
#pragma unroll
        for (int j = 0; j < 4; ++j) {
            int i = wid * 4 + j;
            int p = i * 1024 + 16 * lane;
            int row = p >> 8, cb = p & 255;
            int cbs = cb ^ ((row & 7) << 4);
            int n = kv0 + row; if (n > 1024) n = 1024;
            gload16(kkb + (size_t)(b * N_ + n) * C_ + h * D_ + (cbs >> 1), Ks + i * 512);
        }
        // stage V tile [128][64] from vvT (rows = d, 128B rows)
#pragma unroll
        for (int j = 0; j < 4; ++j) {
            int i = wid * 4 + j;
            int p = i * 1024 + 16 * lane;
            int row = p >> 7, cb = p & 127;
            int cbs = cb ^ ((row & 7) << 4);
            int st = kv0 + (cbs >> 1); if (st > NPAD_ - 8) st = NPAD_ - 8;
            gload16(vvT + (size_t)(bh * D_ + row) * NPAD_ + st, Vs + i * 512);
        }
        __syncthreads();

        // S = Q @ K^T  (4 col-subtiles of 16 kv)
        f32x4 s[4];
#pragma unroll
        for (int jt = 0; jt < 4; ++jt) {
            f32x4 a = FZ;
#pragma unroll
            for (int ks = 0; ks < 4; ++ks) {
                int kvr = jt * 16 + (lane & 15);
                int byte = (kvr * 256 + ks * 64 + (lane >> 4) * 16) ^ ((kvr & 7) << 4);
                bf16x8 kf = *(const bf16x8*)((const char*)Ks + byte);
                a = __builtin_amdgcn_mfma_f32_16x16x32_bf16(qf[ks], kf, a, 0, 0, 0);
            }
            a = a * SCALE;
            int kvglob = kv0 + jt * 16 + (lane & 15);
            if (kvglob > 1024) { a[0] = -3e38f; a[1] = -3e38f; a[2] = -3e38f; a[3] = -3e38f; }
            s[jt] = a;
        }

        // online softmax per row r (rows = (lane>>4)*4 + r, 16 lanes = 16 kv cols each jt)
        float al[4];
#pragma unroll
        for (int r = 0; r < 4; ++r) {
            float tm = fmaxf(fmaxf(s[0][r], s[1][r]), fmaxf(s[2][r], s[3][r]));
#pragma unroll
            for (int off = 1; off < 16; off <<= 1) tm = fmaxf(tm, __shfl_xor(tm, off));
            float mn = fmaxf(mrow[r], tm);
            al[r] = __expf(mrow[r] - mn);
            mrow[r] = mn;
            float ps = 0.f;
#pragma unroll
            for (int jt = 0; jt < 4; ++jt) {
                float p = __expf(s[jt][r] - mn);
                s[jt][r] = p; ps += p;
            }
#pragma unroll
            for (int off = 1; off < 16; off <<= 1) ps += __shfl_xor(ps, off);
            lsum[r] = lsum[r] * al[r] + ps;
        }

        // P -> LDS (bf16, C-layout scatter), rescale O
#pragma unroll
        for (int jt = 0; jt < 4; ++jt)
#pragma unroll
            for (int r = 0; r < 4; ++r) {
                int pr = (lane >> 4) * 4 + r;
                int byte = (pr * 128 + (jt * 16 + (lane & 15)) * 2) ^ ((pr & 7) << 4);
                *(u16*)(psb + byte) = f2bf(s[jt][r]);
            }
#pragma unroll
        for (int ct = 0; ct < 8; ++ct)
#pragma unroll
            for (int r = 0; r < 4; ++r) of[ct][r] *= al[r];

        // PV: O += P @ V
        bf16x8 pa[2];
#pragma unroll
        for (int ks2 = 0; ks2 < 2; ++ks2) {
            int prr = lane & 15;
            int byte = (prr * 128 + ks2 * 64 + (lane >> 4) * 16) ^ ((prr & 7) << 4);
            pa[ks2] = *(const bf16x8*)(psb + byte);
        }
#pragma unroll
        for (int ct = 0; ct < 8; ++ct)
#pragma unroll
            for (int ks2 = 0; ks2 < 2; ++ks2) {
                int d = ct * 16 + (lane & 15);
                int byte = (d * 128 + ks2 * 64 + (lane >> 4) * 16) ^ ((d & 7) << 4);
                bf16x8 vf = *(const bf16x8*)((const char*)Vs + byte);
                of[ct] = __builtin_amdgcn_mfma_f32_16x16x32_bf16(pa[ks2], vf, of[ct], 0, 0, 0);
            }
    }

    // write O / lsum -> ob (bf16)
#pragma unroll
    for (int ct = 0; ct < 8; ++ct)
#pragma unroll
        for (int r = 0; r < 4; ++r) {
            int n = n0q + wid * 16 + (lane >> 4) * 4 + r;
            if (n <= 1024)
                ob[(size_t)(b * N_ + n) * C_ + h * D_ + ct * 16 + (lane & 15)] =
                    f2bf(of[ct][r] / lsum[r]);
        }
}

extern "C" void kernel_launch(void* const* d_in, const int* in_sizes, int n_in,
                              void* d_out, int out_size, void* d_ws, size_t ws_size,
                              hipStream_t stream)
{
    const float* x       = (const float*)d_in[0];
    const float* style_k = (const float*)d_in[1];
    const float* style_v = (const float*)d_in[2];
    const float* W_qkv   = (const float*)d_in[3];
    const float* W_proj  = (const float*)d_in[4];
    const float* b_proj  = (const float*)d_in[5];
    const float* ak      = (const float*)d_in[6];
    const float* bk      = (const float*)d_in[7];
    const float* av      = (const float*)d_in[8];
    const float* bv      = (const float*)d_in[9];
    const float* W1      = (const float*)d_in[10];
    const float* b1      = (const float*)d_in[11];
    const float* W2      = (const float*)d_in[12];
    const float* b2      = (const float*)d_in[13];

    float* outp   = (float*)d_out;
    float* vv_out = outp + (size_t)M_ * C_;   // second tuple output (fp32)

    // scratch in d_out x_return region (dead until final proj GEMM writes it):
    u16* WqkvT = (u16*)outp;                       // 3072*1024
    u16* Tk    = WqkvT + (size_t)3072 * 1024;      // 1024*1024
    u16* Tv    = Tk + (size_t)1024 * 1024;         // 1024*1024   (total 10.5 MB < 33.5 MB)

    // ws layout (bf16 unless noted): ~69.4 MB total
    u16* ws     = (u16*)d_ws;
    u16* qb     = ws;                              // M_*C_
    u16* kkb    = qb  + (size_t)M_ * C_;
    u16* obuf   = kkb + (size_t)M_ * C_;
    u16* vvT    = obuf + (size_t)M_ * C_;          // 64*128*NPAD_
    u16* WprojT = vvT + (size_t)B_ * H_ * D_ * NPAD_;
    float* wcls = (float*)(WprojT + (size_t)1024 * 1024);

    wt_kernel<<<dim3(96, 32), 256, 0, stream>>>(W_qkv, WqkvT, 1024, 3072);
    wt_kernel<<<dim3(32, 32), 256, 0, stream>>>(W_proj, WprojT, 1024, 1024);
    tokens_kernel<<<dim3(4, 1024, 2), 256, 0, stream>>>(ak, bk, av, bv, Tk, Tv);
    se_kernel<<<dim3(B_ * (C_ / 8)), 256, 0, stream>>>(x, W1, b1, W2, b2, wcls);

    qkv_gemm<<<dim3(65, 24), 256, 0, stream>>>(x, style_k, style_v, WqkvT, Tk, Tv,
                                               qb, kkb, vv_out);
    vvt_kernel<<<dim3(33, 4, 64), 256, 0, stream>>>(vv_out, vvT);
    attn_kernel<<<dim3(17, 64), 256, 0, stream>>>(qb, kkb, vvT, obuf);
    proj_gemm<<<dim3(65, 8), 256, 0, stream>>>(obuf, WprojT, b_proj, wcls, outp);
}

// Round 4
// 513.057 us; speedup vs baseline: 9.4778x; 1.1307x over previous
//
#include <hip/hip_runtime.h>
#include <hip/hip_bf16.h>
#include <stdint.h>

#define B_ 8
#define N_ 1025
#define C_ 1024
#define H_ 8
#define D_ 128
#define TOK_ 1024
#define LORA_ 16
#define M_ 8200          // B_*N_
#define NPAD_ 1032       // padded N for vvT rows

using bf16x8 = __attribute__((ext_vector_type(8))) short;
using f32x4  = __attribute__((ext_vector_type(4))) float;
typedef unsigned short u16;

__device__ __forceinline__ u16 f2bf(float f) {
    union { float f; unsigned u; } v; v.f = f;
    unsigned r = v.u + 0x7fffu + ((v.u >> 16) & 1u);   // RNE
    return (u16)(r >> 16);
}

__device__ __forceinline__ void gload16(const u16* g, u16* l) {
    __builtin_amdgcn_global_load_lds(
        (const __attribute__((address_space(1))) void*)g,
        (__attribute__((address_space(3))) void*)l, 16, 0, 0);
}

// bijective XCD swizzle (nwg % 8 == 0)
__device__ __forceinline__ int xcd_swz(int bid, int nwg) {
    int cpx = nwg >> 3;
    return (bid & 7) * cpx + (bid >> 3);
}

// ---------------- fp32 -> bf16 cast (x, style_k, style_v), 8 elems/thread --------------
__global__ __launch_bounds__(256) void cast3_kernel(
    const float* __restrict__ x, const float* __restrict__ sk, const float* __restrict__ sv,
    u16* __restrict__ xb, u16* __restrict__ skb, u16* __restrict__ svb)
{
    const float* in = blockIdx.y == 0 ? x : (blockIdx.y == 1 ? sk : sv);
    u16* out = blockIdx.y == 0 ? xb : (blockIdx.y == 1 ? skb : svb);
    size_t i = (size_t)blockIdx.x * 256 + threadIdx.x;   // covers M_*C_/8 exactly
    float4 a = *((const float4*)in + i * 2);
    float4 b = *((const float4*)in + i * 2 + 1);
    bf16x8 v;
    v[0] = (short)f2bf(a.x); v[1] = (short)f2bf(a.y);
    v[2] = (short)f2bf(a.z); v[3] = (short)f2bf(a.w);
    v[4] = (short)f2bf(b.x); v[5] = (short)f2bf(b.y);
    v[6] = (short)f2bf(b.z); v[7] = (short)f2bf(b.w);
    *(bf16x8*)(out + i * 8) = v;
}

// ---------------- tokens: Tk[t][c] = sum_l ak[t,l]*bk[l,c]  (bf16 B^T layout) ----------
__global__ __launch_bounds__(256) void tokens_kernel(
    const float* __restrict__ ak, const float* __restrict__ bk,
    const float* __restrict__ av, const float* __restrict__ bv,
    u16* __restrict__ Tk, u16* __restrict__ Tv)
{
    const float* a = blockIdx.z ? av : ak;
    const float* b = blockIdx.z ? bv : bk;
    u16* o = blockIdx.z ? Tv : Tk;
    int c = blockIdx.x * 256 + threadIdx.x;
    int t = blockIdx.y;
    float s = 0.f;
#pragma unroll
    for (int l = 0; l < LORA_; ++l) s += a[t * LORA_ + l] * b[l * C_ + c];
    o[(size_t)t * C_ + c] = f2bf(s);
}

// ---------------- weight transpose+cast: in (K x Nw) f32 -> out (Nw x K) bf16 ----------
__global__ __launch_bounds__(256) void wt_kernel(
    const float* __restrict__ in, u16* __restrict__ out, int K, int Nw)
{
    __shared__ float t[32][33];
    int n0 = blockIdx.x * 32, k0 = blockIdx.y * 32;
    int tx = threadIdx.x & 31, ty = threadIdx.x >> 5;
#pragma unroll
    for (int yy = 0; yy < 32; yy += 8)
        t[ty + yy][tx] = in[(size_t)(k0 + ty + yy) * Nw + n0 + tx];
    __syncthreads();
#pragma unroll
    for (int yy = 0; yy < 32; yy += 8)
        out[(size_t)(n0 + ty + yy) * K + k0 + tx] = f2bf(t[tx][ty + yy]);
}

// ---------------- vv (f32) -> vvT bf16 [bh*128+d][NPAD_] -------------------------------
__global__ __launch_bounds__(256) void vvt_kernel(
    const float* __restrict__ vv, u16* __restrict__ vvT)
{
    __shared__ float t[32][33];
    int n0 = blockIdx.x * 32, d0 = blockIdx.y * 32, bh = blockIdx.z;
    int b = bh >> 3, h = bh & 7;
    int tx = threadIdx.x & 31, ty = threadIdx.x >> 5;
#pragma unroll
    for (int yy = 0; yy < 32; yy += 8) {
        int n = n0 + ty + yy; if (n > 1024) n = 1024;
        t[ty + yy][tx] = vv[((size_t)(b * N_) + n) * C_ + h * D_ + d0 + tx];
    }
    __syncthreads();
#pragma unroll
    for (int yy = 0; yy < 32; yy += 8) {
        int n = n0 + tx;
        if (n < NPAD_)
            vvT[((size_t)bh * D_ + d0 + ty + yy) * NPAD_ + n] = f2bf(t[tx][ty + yy]);
    }
}

// ---------------- SE module (fp32) -----------------------------------------------------
__global__ __launch_bounds__(256) void se_kernel(
    const float* __restrict__ x, const float* __restrict__ W1,
    const float* __restrict__ b1, const float* __restrict__ W2,
    const float* __restrict__ b2, float* __restrict__ wcls)
{
    __shared__ float xs[1024][8];
    __shared__ float red[8][257];
    const int tid = threadIdx.x;
    const int b  = blockIdx.x >> 7;
    const int c0 = (blockIdx.x & 127) * 8;
    const float* xb = x + (size_t)b * N_ * C_;
    for (int i = tid; i < 1024 * 8; i += 256) {
        int t = i >> 3, cc = i & 7;
        xs[t][cc] = xb[(size_t)(1 + t) * C_ + c0 + cc];
    }
    __syncthreads();
    float acc[8] = {};
    const int j = tid;
    for (int t = 0; t < 1024; ++t) {
        float w = W1[t * 256 + j];
        const float4* xr = (const float4*)&xs[t][0];
        float4 x0 = xr[0], x1 = xr[1];
        acc[0] += x0.x * w; acc[1] += x0.y * w; acc[2] += x0.z * w; acc[3] += x0.w * w;
        acc[4] += x1.x * w; acc[5] += x1.y * w; acc[6] += x1.z * w; acc[7] += x1.w * w;
    }
    float w2 = W2[j];
#pragma unroll
    for (int cc = 0; cc < 8; ++cc) {
        float h = acc[cc] + b1[j];
        h = h > 0.f ? h : 0.f;
        red[cc][j] = h * w2;
    }
    __syncthreads();
    if (tid < 8) {
        float s = 0.f;
        for (int jj = 0; jj < 256; ++jj) s += red[tid][jj];
        float aw = 1.f / (1.f + expf(-(s + b2[0])));
        wcls[b * C_ + c0 + tid] = xb[c0 + tid] * aw;
    }
}

// ---------------- MFMA GEMM core (bf16 A and B, both via global_load_lds) --------------
// Tile 128x128, BK=64. LDS tile rows = 128 B, XOR-swizzle byte^((row&7)<<4).
// Each operand tile = 128 rows x 64 k x 2B = 16 KB = 8192 u16.  (Round-3 bug: was 4096.)
__device__ __forceinline__ void stage_tile(
    const u16* __restrict__ base, int row0, int maxrow,
    u16* lds, int k0, int lane, int wid)
{
#pragma unroll
    for (int j = 0; j < 4; ++j) {
        int i = wid * 4 + j;
        int p = i * 1024 + 16 * lane;           // linear LDS byte this lane fills
        int row = p >> 7, cb = p & 127;
        int cbs = cb ^ ((row & 7) << 4);        // inverse-swizzled source column
        int gr = row0 + row; if (gr > maxrow) gr = maxrow;
        gload16(base + (size_t)gr * 1024 + k0 + (cbs >> 1), lds + i * 512);
    }
}

__device__ __forceinline__ void gemm_pass(
    const u16* __restrict__ A, const u16* __restrict__ Bt, int row0, int nb0,
    u16* As, u16* Bs, f32x4 acc[4][4],
    const int lane, const int wid, const int wr, const int wc)
{
    for (int k0 = 0; k0 < 1024; k0 += 64) {
        __syncthreads();
        stage_tile(A,  row0, M_ - 1,    As, k0, lane, wid);
        stage_tile(Bt, nb0,  (1 << 30), Bs, k0, lane, wid);
        __syncthreads();
#pragma unroll
        for (int ks = 0; ks < 2; ++ks) {
            bf16x8 af[4], bfr[4];
#pragma unroll
            for (int mi = 0; mi < 4; ++mi) {
                int r = wr * 64 + mi * 16 + (lane & 15);
                int byte = (r * 128 + ks * 64 + (lane >> 4) * 16) ^ ((r & 7) << 4);
                af[mi] = *(const bf16x8*)((const char*)As + byte);
            }
#pragma unroll
            for (int ni = 0; ni < 4; ++ni) {
                int r = wc * 64 + ni * 16 + (lane & 15);
                int byte = (r * 128 + ks * 64 + (lane >> 4) * 16) ^ ((r & 7) << 4);
                bfr[ni] = *(const bf16x8*)((const char*)Bs + byte);
            }
#pragma unroll
            for (int mi = 0; mi < 4; ++mi)
#pragma unroll
                for (int ni = 0; ni < 4; ++ni)
                    acc[mi][ni] = __builtin_amdgcn_mfma_f32_16x16x32_bf16(
                        af[mi], bfr[ni], acc[mi][ni], 0, 0, 0);
        }
    }
}

// ---------------- fused qkv GEMM: regions q / kk(+lora) / vv(+lora) --------------------
__global__ __launch_bounds__(256) void qkv_gemm(
    const u16* __restrict__ xb, const u16* __restrict__ skb, const u16* __restrict__ svb,
    const u16* __restrict__ WqkvT, const u16* __restrict__ Tk, const u16* __restrict__ Tv,
    u16* __restrict__ qb, u16* __restrict__ kkb, float* __restrict__ vvout)
{
    __shared__ u16 As[8192], Bs[8192];
    const int tid = threadIdx.x, lane = tid & 63, wid = tid >> 6;
    const int wr = wid >> 1, wc = wid & 1;
    const int swz = xcd_swz(blockIdx.x, 65 * 24);
    const int row0 = (swz % 65) * 128;
    const int ct = swz / 65, region = ct >> 3;
    const f32x4 FZ = {0.f, 0.f, 0.f, 0.f};
    f32x4 acc[4][4];
#pragma unroll
    for (int mi = 0; mi < 4; ++mi)
#pragma unroll
        for (int ni = 0; ni < 4; ++ni) acc[mi][ni] = FZ;

    gemm_pass(xb, WqkvT, row0, ct * 128, As, Bs, acc, lane, wid, wr, wc);
    if (region == 1) gemm_pass(skb, Tk, row0, (ct & 7) * 128, As, Bs, acc, lane, wid, wr, wc);
    if (region == 2) gemm_pass(svb, Tv, row0, (ct & 7) * 128, As, Bs, acc, lane, wid, wr, wc);

    const int creg = (ct & 7) * 128;
#pragma unroll
    for (int mi = 0; mi < 4; ++mi) {
#pragma unroll
        for (int r = 0; r < 4; ++r) {
            int gr = row0 + wr * 64 + mi * 16 + (lane >> 4) * 4 + r;
            if (gr >= M_) continue;
#pragma unroll
            for (int ni = 0; ni < 4; ++ni) {
                int gc = creg + wc * 64 + ni * 16 + (lane & 15);
                float v = acc[mi][ni][r];
                if (region == 0)      qb [(size_t)gr * C_ + gc] = f2bf(v);
                else if (region == 1) kkb[(size_t)gr * C_ + gc] = f2bf(v);
                else                  vvout[(size_t)gr * C_ + gc] = v;
            }
        }
    }
}

// ---------------- proj GEMM: out = ob @ WprojT^T + b_proj (+wcls on cls rows) ----------
__global__ __launch_bounds__(256) void proj_gemm(
    const u16* __restrict__ ob, const u16* __restrict__ WprojT,
    const float* __restrict__ bias, const float* __restrict__ wcls,
    float* __restrict__ outp)
{
    __shared__ u16 As[8192], Bs[8192];
    const int tid = threadIdx.x, lane = tid & 63, wid = tid >> 6;
    const int wr = wid >> 1, wc = wid & 1;
    const int swz = xcd_swz(blockIdx.x, 65 * 8);
    const int row0 = (swz % 65) * 128;
    const int ct = swz / 65;
    const f32x4 FZ = {0.f, 0.f, 0.f, 0.f};
    f32x4 acc[4][4];
#pragma unroll
    for (int mi = 0; mi < 4; ++mi)
#pragma unroll
        for (int ni = 0; ni < 4; ++ni) acc[mi][ni] = FZ;

    gemm_pass(ob, WprojT, row0, ct * 128, As, Bs, acc, lane, wid, wr, wc);

#pragma unroll
    for (int mi = 0; mi < 4; ++mi) {
#pragma unroll
        for (int r = 0; r < 4; ++r) {
            int gr = row0 + wr * 64 + mi * 16 + (lane >> 4) * 4 + r;
            if (gr >= M_) continue;
#pragma unroll
            for (int ni = 0; ni < 4; ++ni) {
                int gc = ct * 128 + wc * 64 + ni * 16 + (lane & 15);
                float v = acc[mi][ni][r] + bias[gc];
                if (gr % N_ == 0) v += wcls[(gr / N_) * C_ + gc];
                outp[(size_t)gr * C_ + gc] = v;
            }
        }
    }
}

// ---------------- flash attention, bf16 MFMA -------------------------------------------
__global__ __launch_bounds__(256) void attn_kernel(
    const u16* __restrict__ qb, const u16* __restrict__ kkb,
    const u16* __restrict__ vvT, u16* __restrict__ ob)
{
    __shared__ u16 Ks[8192];   // [64 kv][128 d], swizzled
    __shared__ u16 Vs[8192];   // [128 d][64 kv], swizzled
    __shared__ u16 Ps[4096];   // per-wave [16 q][64 kv], swizzled
    const int tid = threadIdx.x, lane = tid & 63, wid = tid >> 6;
    const int swz = xcd_swz(blockIdx.x, 17 * 64);
    const int qt = swz % 17, bh = swz / 17, b = bh >> 3, h = bh & 7;
    const int n0q = qt * 64;
    const float SCALE = 0.08838834764831845f;

    bf16x8 qf[4];
    {
        int qrow = n0q + wid * 16 + (lane & 15); if (qrow > 1024) qrow = 1024;
        const u16* qbase = qb + (size_t)(b * N_ + qrow) * C_ + h * D_ + (lane >> 4) * 8;
#pragma unroll
        for (int ks = 0; ks < 4; ++ks) qf[ks] = *(const bf16x8*)(qbase + ks * 32);
    }

    float mrow[4], lsum[4];
    const f32x4 FZ = {0.f, 0.f, 0.f, 0.f};
    f32x4 of[8];
#pragma unroll
    for (int r = 0; r < 4; ++r) { mrow[r] = -3e38f; lsum[r] = 0.f; }
#pragma unroll
    for (int ct = 0; ct < 8; ++ct) of[ct] = FZ;

    char* psb = (char*)Ps + wid * 2048;

    for (int t = 0; t < 17; ++t) {
        const int kv0 = t * 64;
        __syncthreads();
#pragma unroll
        for (int j = 0; j < 4; ++j) {
            int i = wid * 4 + j;
            int p = i * 1024 + 16 * lane;
            int row = p >> 8, cb = p & 255;
            int cbs = cb ^ ((row & 7) << 4);
            int n = kv0 + row; if (n > 1024) n = 1024;
            gload16(kkb + (size_t)(b * N_ + n) * C_ + h * D_ + (cbs >> 1), Ks + i * 512);
        }
#pragma unroll
        for (int j = 0; j < 4; ++j) {
            int i = wid * 4 + j;
            int p = i * 1024 + 16 * lane;
            int row = p >> 7, cb = p & 127;
            int cbs = cb ^ ((row & 7) << 4);
            int st = kv0 + (cbs >> 1); if (st > NPAD_ - 8) st = NPAD_ - 8;
            gload16(vvT + (size_t)(bh * D_ + row) * NPAD_ + st, Vs + i * 512);
        }
        __syncthreads();

        f32x4 s[4];
#pragma unroll
        for (int jt = 0; jt < 4; ++jt) {
            f32x4 a = FZ;
#pragma unroll
            for (int ks = 0; ks < 4; ++ks) {
                int kvr = jt * 16 + (lane & 15);
                int byte = (kvr * 256 + ks * 64 + (lane >> 4) * 16) ^ ((kvr & 7) << 4);
                bf16x8 kf = *(const bf16x8*)((const char*)Ks + byte);
                a = __builtin_amdgcn_mfma_f32_16x16x32_bf16(qf[ks], kf, a, 0, 0, 0);
            }
            a = a * SCALE;
            int kvglob = kv0 + jt * 16 + (lane & 15);
            if (kvglob > 1024) { a[0] = -3e38f; a[1] = -3e38f; a[2] = -3e38f; a[3] = -3e38f; }
            s[jt] = a;
        }

        float al[4];
#pragma unroll
        for (int r = 0; r < 4; ++r) {
            float tm = fmaxf(fmaxf(s[0][r], s[1][r]), fmaxf(s[2][r], s[3][r]));
#pragma unroll
            for (int off = 1; off < 16; off <<= 1) tm = fmaxf(tm, __shfl_xor(tm, off));
            float mn = fmaxf(mrow[r], tm);
            al[r] = __expf(mrow[r] - mn);
            mrow[r] = mn;
            float ps = 0.f;
#pragma unroll
            for (int jt = 0; jt < 4; ++jt) {
                float p = __expf(s[jt][r] - mn);
                s[jt][r] = p; ps += p;
            }
#pragma unroll
            for (int off = 1; off < 16; off <<= 1) ps += __shfl_xor(ps, off);
            lsum[r] = lsum[r] * al[r] + ps;
        }

#pragma unroll
        for (int jt = 0; jt < 4; ++jt)
#pragma unroll
            for (int r = 0; r < 4; ++r) {
                int pr = (lane >> 4) * 4 + r;
                int byte = (pr * 128 + (jt * 16 + (lane & 15)) * 2) ^ ((pr & 7) << 4);
                *(u16*)(psb + byte) = f2bf(s[jt][r]);
            }
#pragma unroll
        for (int ct = 0; ct < 8; ++ct)
#pragma unroll
            for (int r = 0; r < 4; ++r) of[ct][r] *= al[r];

        bf16x8 pa[2];
#pragma unroll
        for (int ks2 = 0; ks2 < 2; ++ks2) {
            int prr = lane & 15;
            int byte = (prr * 128 + ks2 * 64 + (lane >> 4) * 16) ^ ((prr & 7) << 4);
            pa[ks2] = *(const bf16x8*)(psb + byte);
        }
#pragma unroll
        for (int ct = 0; ct < 8; ++ct)
#pragma unroll
            for (int ks2 = 0; ks2 < 2; ++ks2) {
                int d = ct * 16 + (lane & 15);
                int byte = (d * 128 + ks2 * 64 + (lane >> 4) * 16) ^ ((d & 7) << 4);
                bf16x8 vf = *(const bf16x8*)((const char*)Vs + byte);
                of[ct] = __builtin_amdgcn_mfma_f32_16x16x32_bf16(pa[ks2], vf, of[ct], 0, 0, 0);
            }
    }

#pragma unroll
    for (int ct = 0; ct < 8; ++ct)
#pragma unroll
        for (int r = 0; r < 4; ++r) {
            int n = n0q + wid * 16 + (lane >> 4) * 4 + r;
            if (n <= 1024)
                ob[(size_t)(b * N_ + n) * C_ + h * D_ + ct * 16 + (lane & 15)] =
                    f2bf(of[ct][r] / lsum[r]);
        }
}

extern "C" void kernel_launch(void* const* d_in, const int* in_sizes, int n_in,
                              void* d_out, int out_size, void* d_ws, size_t ws_size,
                              hipStream_t stream)
{
    const float* x       = (const float*)d_in[0];
    const float* style_k = (const float*)d_in[1];
    const float* style_v = (const float*)d_in[2];
    const float* W_qkv   = (const float*)d_in[3];
    const float* W_proj  = (const float*)d_in[4];
    const float* b_proj  = (const float*)d_in[5];
    const float* ak      = (const float*)d_in[6];
    const float* bk      = (const float*)d_in[7];
    const float* av      = (const float*)d_in[8];
    const float* bv      = (const float*)d_in[9];
    const float* W1      = (const float*)d_in[10];
    const float* b1      = (const float*)d_in[11];
    const float* W2      = (const float*)d_in[12];
    const float* b2      = (const float*)d_in[13];

    float* outp   = (float*)d_out;
    float* vv_out = outp + (size_t)M_ * C_;        // second tuple output (fp32)

    // scratch parked in d_out x_return region (dead until proj_gemm writes it):
    u16* WqkvT = (u16*)outp;                       // 3072*1024
    u16* Tk    = WqkvT + (size_t)3072 * 1024;      // 1024*1024
    u16* Tv    = Tk + (size_t)1024 * 1024;         // 1024*1024
    u16* xbb   = Tv + (size_t)1024 * 1024;         // M_*C_ bf16 (ends at 27.3MB < 33.6MB)

    // ws layout (u16 units): ~69.4 MB
    u16* ws     = (u16*)d_ws;
    u16* qb     = ws;                              // M_*C_
    u16* kkb    = qb  + (size_t)M_ * C_;           // M_*C_
    u16* obuf   = kkb + (size_t)M_ * C_;           // M_*C_  (aliases skb during qkv)
    u16* vvT    = obuf + (size_t)M_ * C_;          // 64*128*NPAD_ (aliases svb during qkv)
    u16* WprojT = vvT + (size_t)B_ * H_ * D_ * NPAD_;
    float* wcls = (float*)(WprojT + (size_t)1024 * 1024);
    u16* skb = obuf;   // lifetime: cast3 .. qkv   (attn writes obuf later)
    u16* svb = vvT;    // lifetime: cast3 .. qkv   (vvt writes vvT later)

    wt_kernel<<<dim3(96, 32), 256, 0, stream>>>(W_qkv, WqkvT, 1024, 3072);
    wt_kernel<<<dim3(32, 32), 256, 0, stream>>>(W_proj, WprojT, 1024, 1024);
    tokens_kernel<<<dim3(4, 1024, 2), 256, 0, stream>>>(ak, bk, av, bv, Tk, Tv);
    cast3_kernel<<<dim3(4100, 3), 256, 0, stream>>>(x, style_k, style_v, xbb, skb, svb);
    se_kernel<<<dim3(B_ * (C_ / 8)), 256, 0, stream>>>(x, W1, b1, W2, b2, wcls);

    qkv_gemm<<<dim3(65 * 24), 256, 0, stream>>>(xbb, skb, svb, WqkvT, Tk, Tv,
                                                qb, kkb, vv_out);
    vvt_kernel<<<dim3(33, 4, 64), 256, 0, stream>>>(vv_out, vvT);
    attn_kernel<<<dim3(17 * 64), 256, 0, stream>>>(qb, kkb, vvT, obuf);
    proj_gemm<<<dim3(65 * 8), 256, 0, stream>>>(obuf, WprojT, b_proj, wcls, outp);
}

// Round 5
// 465.364 us; speedup vs baseline: 10.4491x; 1.1025x over previous
//
#include <hip/hip_runtime.h>
#include <hip/hip_bf16.h>
#include <stdint.h>

#define B_ 8
#define N_ 1025
#define C_ 1024
#define H_ 8
#define D_ 128
#define TOK_ 1024
#define LORA_ 16
#define M_ 8200          // B_*N_
#define NPAD_ 1032       // padded N for vvT rows

using bf16x8 = __attribute__((ext_vector_type(8))) short;
using f32x4  = __attribute__((ext_vector_type(4))) float;
typedef unsigned short u16;

__device__ __forceinline__ u16 f2bf(float f) {
    union { float f; unsigned u; } v; v.f = f;
    unsigned r = v.u + 0x7fffu + ((v.u >> 16) & 1u);   // RNE
    return (u16)(r >> 16);
}

__device__ __forceinline__ void gload16(const u16* g, u16* l) {
    __builtin_amdgcn_global_load_lds(
        (const __attribute__((address_space(1))) void*)g,
        (__attribute__((address_space(3))) void*)l, 16, 0, 0);
}

// bijective XCD swizzle (nwg % 8 == 0)
__device__ __forceinline__ int xcd_swz(int bid, int nwg) {
    int cpx = nwg >> 3;
    return (bid & 7) * cpx + (bid >> 3);
}

// ---------------- fp32 -> bf16 cast (x, style_k, style_v), 8 elems/thread --------------
__global__ __launch_bounds__(256) void cast3_kernel(
    const float* __restrict__ x, const float* __restrict__ sk, const float* __restrict__ sv,
    u16* __restrict__ xb, u16* __restrict__ skb, u16* __restrict__ svb)
{
    const float* in = blockIdx.y == 0 ? x : (blockIdx.y == 1 ? sk : sv);
    u16* out = blockIdx.y == 0 ? xb : (blockIdx.y == 1 ? skb : svb);
    size_t i = (size_t)blockIdx.x * 256 + threadIdx.x;   // covers M_*C_/8 exactly
    float4 a = *((const float4*)in + i * 2);
    float4 b = *((const float4*)in + i * 2 + 1);
    bf16x8 v;
    v[0] = (short)f2bf(a.x); v[1] = (short)f2bf(a.y);
    v[2] = (short)f2bf(a.z); v[3] = (short)f2bf(a.w);
    v[4] = (short)f2bf(b.x); v[5] = (short)f2bf(b.y);
    v[6] = (short)f2bf(b.z); v[7] = (short)f2bf(b.w);
    *(bf16x8*)(out + i * 8) = v;
}

// ---------------- tokens: Tk[t][c] = sum_l ak[t,l]*bk[l,c]  (bf16 B^T layout) ----------
__global__ __launch_bounds__(256) void tokens_kernel(
    const float* __restrict__ ak, const float* __restrict__ bk,
    const float* __restrict__ av, const float* __restrict__ bv,
    u16* __restrict__ Tk, u16* __restrict__ Tv)
{
    const float* a = blockIdx.z ? av : ak;
    const float* b = blockIdx.z ? bv : bk;
    u16* o = blockIdx.z ? Tv : Tk;
    int c = blockIdx.x * 256 + threadIdx.x;
    int t = blockIdx.y;
    float s = 0.f;
#pragma unroll
    for (int l = 0; l < LORA_; ++l) s += a[t * LORA_ + l] * b[l * C_ + c];
    o[(size_t)t * C_ + c] = f2bf(s);
}

// ---------------- weight transpose+cast: in (K x Nw) f32 -> out (Nw x K) bf16 ----------
__global__ __launch_bounds__(256) void wt_kernel(
    const float* __restrict__ in, u16* __restrict__ out, int K, int Nw)
{
    __shared__ float t[32][33];
    int n0 = blockIdx.x * 32, k0 = blockIdx.y * 32;
    int tx = threadIdx.x & 31, ty = threadIdx.x >> 5;
#pragma unroll
    for (int yy = 0; yy < 32; yy += 8)
        t[ty + yy][tx] = in[(size_t)(k0 + ty + yy) * Nw + n0 + tx];
    __syncthreads();
#pragma unroll
    for (int yy = 0; yy < 32; yy += 8)
        out[(size_t)(n0 + ty + yy) * K + k0 + tx] = f2bf(t[tx][ty + yy]);
}

// ---------------- vv (f32) -> vvT bf16 [bh*128+d][NPAD_] -------------------------------
__global__ __launch_bounds__(256) void vvt_kernel(
    const float* __restrict__ vv, u16* __restrict__ vvT)
{
    __shared__ float t[32][33];
    int n0 = blockIdx.x * 32, d0 = blockIdx.y * 32, bh = blockIdx.z;
    int b = bh >> 3, h = bh & 7;
    int tx = threadIdx.x & 31, ty = threadIdx.x >> 5;
#pragma unroll
    for (int yy = 0; yy < 32; yy += 8) {
        int n = n0 + ty + yy; if (n > 1024) n = 1024;
        t[ty + yy][tx] = vv[((size_t)(b * N_) + n) * C_ + h * D_ + d0 + tx];
    }
    __syncthreads();
#pragma unroll
    for (int yy = 0; yy < 32; yy += 8) {
        int n = n0 + tx;
        if (n < NPAD_)
            vvT[((size_t)bh * D_ + d0 + ty + yy) * NPAD_ + n] = f2bf(t[tx][ty + yy]);
    }
}

// ---------------- SE module (fp32) -----------------------------------------------------
__global__ __launch_bounds__(256) void se_kernel(
    const float* __restrict__ x, const float* __restrict__ W1,
    const float* __restrict__ b1, const float* __restrict__ W2,
    const float* __restrict__ b2, float* __restrict__ wcls)
{
    __shared__ float xs[1024][8];
    __shared__ float red[8][257];
    const int tid = threadIdx.x;
    const int b  = blockIdx.x >> 7;
    const int c0 = (blockIdx.x & 127) * 8;
    const float* xb = x + (size_t)b * N_ * C_;
    for (int i = tid; i < 1024 * 8; i += 256) {
        int t = i >> 3, cc = i & 7;
        xs[t][cc] = xb[(size_t)(1 + t) * C_ + c0 + cc];
    }
    __syncthreads();
    float acc[8] = {};
    const int j = tid;
    for (int t = 0; t < 1024; ++t) {
        float w = W1[t * 256 + j];
        const float4* xr = (const float4*)&xs[t][0];
        float4 x0 = xr[0], x1 = xr[1];
        acc[0] += x0.x * w; acc[1] += x0.y * w; acc[2] += x0.z * w; acc[3] += x0.w * w;
        acc[4] += x1.x * w; acc[5] += x1.y * w; acc[6] += x1.z * w; acc[7] += x1.w * w;
    }
    float w2 = W2[j];
#pragma unroll
    for (int cc = 0; cc < 8; ++cc) {
        float h = acc[cc] + b1[j];
        h = h > 0.f ? h : 0.f;
        red[cc][j] = h * w2;
    }
    __syncthreads();
    if (tid < 8) {
        float s = 0.f;
        for (int jj = 0; jj < 256; ++jj) s += red[tid][jj];
        float aw = 1.f / (1.f + expf(-(s + b2[0])));
        wcls[b * C_ + c0 + tid] = xb[c0 + tid] * aw;
    }
}

// ---------------- MFMA GEMM core (bf16 A and B, both via global_load_lds) --------------
// Tile 128x128, BK=64. LDS tile rows = 128 B, XOR-swizzle byte^((row&7)<<4).
__device__ __forceinline__ void stage_tile(
    const u16* __restrict__ base, int row0, int maxrow,
    u16* lds, int k0, int lane, int wid)
{
#pragma unroll
    for (int j = 0; j < 4; ++j) {
        int i = wid * 4 + j;
        int p = i * 1024 + 16 * lane;           // linear LDS byte this lane fills
        int row = p >> 7, cb = p & 127;
        int cbs = cb ^ ((row & 7) << 4);        // inverse-swizzled source column
        int gr = row0 + row; if (gr > maxrow) gr = maxrow;
        gload16(base + (size_t)gr * 1024 + k0 + (cbs >> 1), lds + i * 512);
    }
}

__device__ __forceinline__ void gemm_pass(
    const u16* __restrict__ A, const u16* __restrict__ Bt, int row0, int nb0,
    u16* As, u16* Bs, f32x4 acc[4][4],
    const int lane, const int wid, const int wr, const int wc)
{
    for (int k0 = 0; k0 < 1024; k0 += 64) {
        __syncthreads();
        stage_tile(A,  row0, M_ - 1,    As, k0, lane, wid);
        stage_tile(Bt, nb0,  (1 << 30), Bs, k0, lane, wid);
        __syncthreads();
#pragma unroll
        for (int ks = 0; ks < 2; ++ks) {
            bf16x8 af[4], bfr[4];
#pragma unroll
            for (int mi = 0; mi < 4; ++mi) {
                int r = wr * 64 + mi * 16 + (lane & 15);
                int byte = (r * 128 + ks * 64 + (lane >> 4) * 16) ^ ((r & 7) << 4);
                af[mi] = *(const bf16x8*)((const char*)As + byte);
            }
#pragma unroll
            for (int ni = 0; ni < 4; ++ni) {
                int r = wc * 64 + ni * 16 + (lane & 15);
                int byte = (r * 128 + ks * 64 + (lane >> 4) * 16) ^ ((r & 7) << 4);
                bfr[ni] = *(const bf16x8*)((const char*)Bs + byte);
            }
#pragma unroll
            for (int mi = 0; mi < 4; ++mi)
#pragma unroll
                for (int ni = 0; ni < 4; ++ni)
                    acc[mi][ni] = __builtin_amdgcn_mfma_f32_16x16x32_bf16(
                        af[mi], bfr[ni], acc[mi][ni], 0, 0, 0);
        }
    }
}

// ---------------- fused qkv GEMM: regions q / kk(+lora) / vv(+lora) --------------------
// Block order: row-panel-major within each XCD chunk so the ~24 co-resident blocks on an
// XCD share the same A row-panel in that XCD's L2 (A is the expensive stream; B is ~10MB).
__global__ __launch_bounds__(256) void qkv_gemm(
    const u16* __restrict__ xb, const u16* __restrict__ skb, const u16* __restrict__ svb,
    const u16* __restrict__ WqkvT, const u16* __restrict__ Tk, const u16* __restrict__ Tv,
    u16* __restrict__ qb, u16* __restrict__ kkb, float* __restrict__ vvout)
{
    __shared__ u16 As[8192], Bs[8192];
    const int tid = threadIdx.x, lane = tid & 63, wid = tid >> 6;
    const int wr = wid >> 1, wc = wid & 1;
    const int swz = xcd_swz(blockIdx.x, 65 * 24);
    const int row0 = (swz / 24) * 128;          // A-locality: ct fastest
    const int ct = swz % 24, region = ct >> 3;
    const f32x4 FZ = {0.f, 0.f, 0.f, 0.f};
    f32x4 acc[4][4];
#pragma unroll
    for (int mi = 0; mi < 4; ++mi)
#pragma unroll
        for (int ni = 0; ni < 4; ++ni) acc[mi][ni] = FZ;

    gemm_pass(xb, WqkvT, row0, ct * 128, As, Bs, acc, lane, wid, wr, wc);
    if (region == 1) gemm_pass(skb, Tk, row0, (ct & 7) * 128, As, Bs, acc, lane, wid, wr, wc);
    if (region == 2) gemm_pass(svb, Tv, row0, (ct & 7) * 128, As, Bs, acc, lane, wid, wr, wc);

    const int creg = (ct & 7) * 128;
#pragma unroll
    for (int mi = 0; mi < 4; ++mi) {
#pragma unroll
        for (int r = 0; r < 4; ++r) {
            int gr = row0 + wr * 64 + mi * 16 + (lane >> 4) * 4 + r;
            if (gr >= M_) continue;
#pragma unroll
            for (int ni = 0; ni < 4; ++ni) {
                int gc = creg + wc * 64 + ni * 16 + (lane & 15);
                float v = acc[mi][ni][r];
                if (region == 0)      qb [(size_t)gr * C_ + gc] = f2bf(v);
                else if (region == 1) kkb[(size_t)gr * C_ + gc] = f2bf(v);
                else                  vvout[(size_t)gr * C_ + gc] = v;
            }
        }
    }
}

// ---------------- proj GEMM: out = ob @ WprojT^T + b_proj (+wcls on cls rows) ----------
__global__ __launch_bounds__(256) void proj_gemm(
    const u16* __restrict__ ob, const u16* __restrict__ WprojT,
    const float* __restrict__ bias, const float* __restrict__ wcls,
    float* __restrict__ outp)
{
    __shared__ u16 As[8192], Bs[8192];
    const int tid = threadIdx.x, lane = tid & 63, wid = tid >> 6;
    const int wr = wid >> 1, wc = wid & 1;
    const int swz = xcd_swz(blockIdx.x, 65 * 8);
    const int row0 = (swz / 8) * 128;           // A-locality: ct fastest
    const int ct = swz % 8;
    const f32x4 FZ = {0.f, 0.f, 0.f, 0.f};
    f32x4 acc[4][4];
#pragma unroll
    for (int mi = 0; mi < 4; ++mi)
#pragma unroll
        for (int ni = 0; ni < 4; ++ni) acc[mi][ni] = FZ;

    gemm_pass(ob, WprojT, row0, ct * 128, As, Bs, acc, lane, wid, wr, wc);

#pragma unroll
    for (int mi = 0; mi < 4; ++mi) {
#pragma unroll
        for (int r = 0; r < 4; ++r) {
            int gr = row0 + wr * 64 + mi * 16 + (lane >> 4) * 4 + r;
            if (gr >= M_) continue;
#pragma unroll
            for (int ni = 0; ni < 4; ++ni) {
                int gc = ct * 128 + wc * 64 + ni * 16 + (lane & 15);
                float v = acc[mi][ni][r] + bias[gc];
                if (gr % N_ == 0) v += wcls[(gr / N_) * C_ + gc];
                outp[(size_t)gr * C_ + gc] = v;
            }
        }
    }
}

// ---------------- flash attention, bf16 MFMA -------------------------------------------
__global__ __launch_bounds__(256) void attn_kernel(
    const u16* __restrict__ qb, const u16* __restrict__ kkb,
    const u16* __restrict__ vvT, u16* __restrict__ ob)
{
    __shared__ u16 Ks[8192];   // [64 kv][128 d], swizzled
    __shared__ u16 Vs[8192];   // [128 d][64 kv], swizzled
    __shared__ u16 Ps[4096];   // per-wave [16 q][64 kv], swizzled
    const int tid = threadIdx.x, lane = tid & 63, wid = tid >> 6;
    const int swz = xcd_swz(blockIdx.x, 17 * 64);
    const int qt = swz % 17, bh = swz / 17, b = bh >> 3, h = bh & 7;
    const int n0q = qt * 64;
    const float SCALE = 0.08838834764831845f;

    bf16x8 qf[4];
    {
        int qrow = n0q + wid * 16 + (lane & 15); if (qrow > 1024) qrow = 1024;
        const u16* qbase = qb + (size_t)(b * N_ + qrow) * C_ + h * D_ + (lane >> 4) * 8;
#pragma unroll
        for (int ks = 0; ks < 4; ++ks) qf[ks] = *(const bf16x8*)(qbase + ks * 32);
    }

    float mrow[4], lsum[4];
    const f32x4 FZ = {0.f, 0.f, 0.f, 0.f};
    f32x4 of[8];
#pragma unroll
    for (int r = 0; r < 4; ++r) { mrow[r] = -3e38f; lsum[r] = 0.f; }
#pragma unroll
    for (int ct = 0; ct < 8; ++ct) of[ct] = FZ;

    char* psb = (char*)Ps + wid * 2048;

    for (int t = 0; t < 17; ++t) {
        const int kv0 = t * 64;
        __syncthreads();
#pragma unroll
        for (int j = 0; j < 4; ++j) {
            int i = wid * 4 + j;
            int p = i * 1024 + 16 * lane;
            int row = p >> 8, cb = p & 255;
            int cbs = cb ^ ((row & 7) << 4);
            int n = kv0 + row; if (n > 1024) n = 1024;
            gload16(kkb + (size_t)(b * N_ + n) * C_ + h * D_ + (cbs >> 1), Ks + i * 512);
        }
#pragma unroll
        for (int j = 0; j < 4; ++j) {
            int i = wid * 4 + j;
            int p = i * 1024 + 16 * lane;
            int row = p >> 7, cb = p & 127;
            int cbs = cb ^ ((row & 7) << 4);
            int st = kv0 + (cbs >> 1); if (st > NPAD_ - 8) st = NPAD_ - 8;
            gload16(vvT + (size_t)(bh * D_ + row) * NPAD_ + st, Vs + i * 512);
        }
        __syncthreads();

        f32x4 s[4];
        __builtin_amdgcn_s_setprio(1);
#pragma unroll
        for (int jt = 0; jt < 4; ++jt) {
            f32x4 a = FZ;
#pragma unroll
            for (int ks = 0; ks < 4; ++ks) {
                int kvr = jt * 16 + (lane & 15);
                int byte = (kvr * 256 + ks * 64 + (lane >> 4) * 16) ^ ((kvr & 7) << 4);
                bf16x8 kf = *(const bf16x8*)((const char*)Ks + byte);
                a = __builtin_amdgcn_mfma_f32_16x16x32_bf16(qf[ks], kf, a, 0, 0, 0);
            }
            s[jt] = a;
        }
        __builtin_amdgcn_s_setprio(0);
#pragma unroll
        for (int jt = 0; jt < 4; ++jt) {
            f32x4 a = s[jt] * SCALE;
            int kvglob = kv0 + jt * 16 + (lane & 15);
            if (kvglob > 1024) { a[0] = -3e38f; a[1] = -3e38f; a[2] = -3e38f; a[3] = -3e38f; }
            s[jt] = a;
        }

        float al[4];
#pragma unroll
        for (int r = 0; r < 4; ++r) {
            float tm = fmaxf(fmaxf(s[0][r], s[1][r]), fmaxf(s[2][r], s[3][r]));
#pragma unroll
            for (int off = 1; off < 16; off <<= 1) tm = fmaxf(tm, __shfl_xor(tm, off));
            float mn = fmaxf(mrow[r], tm);
            al[r] = __expf(mrow[r] - mn);
            mrow[r] = mn;
            float ps = 0.f;
#pragma unroll
            for (int jt = 0; jt < 4; ++jt) {
                float p = __expf(s[jt][r] - mn);
                s[jt][r] = p; ps += p;
            }
#pragma unroll
            for (int off = 1; off < 16; off <<= 1) ps += __shfl_xor(ps, off);
            lsum[r] = lsum[r] * al[r] + ps;
        }

#pragma unroll
        for (int jt = 0; jt < 4; ++jt)
#pragma unroll
            for (int r = 0; r < 4; ++r) {
                int pr = (lane >> 4) * 4 + r;
                int byte = (pr * 128 + (jt * 16 + (lane & 15)) * 2) ^ ((pr & 7) << 4);
                *(u16*)(psb + byte) = f2bf(s[jt][r]);
            }
#pragma unroll
        for (int ct = 0; ct < 8; ++ct)
#pragma unroll
            for (int r = 0; r < 4; ++r) of[ct][r] *= al[r];

        bf16x8 pa[2];
#pragma unroll
        for (int ks2 = 0; ks2 < 2; ++ks2) {
            int prr = lane & 15;
            int byte = (prr * 128 + ks2 * 64 + (lane >> 4) * 16) ^ ((prr & 7) << 4);
            pa[ks2] = *(const bf16x8*)(psb + byte);
        }
        __builtin_amdgcn_s_setprio(1);
#pragma unroll
        for (int ct = 0; ct < 8; ++ct)
#pragma unroll
            for (int ks2 = 0; ks2 < 2; ++ks2) {
                int d = ct * 16 + (lane & 15);
                int byte = (d * 128 + ks2 * 64 + (lane >> 4) * 16) ^ ((d & 7) << 4);
                bf16x8 vf = *(const bf16x8*)((const char*)Vs + byte);
                of[ct] = __builtin_amdgcn_mfma_f32_16x16x32_bf16(pa[ks2], vf, of[ct], 0, 0, 0);
            }
        __builtin_amdgcn_s_setprio(0);
    }

#pragma unroll
    for (int ct = 0; ct < 8; ++ct)
#pragma unroll
        for (int r = 0; r < 4; ++r) {
            int n = n0q + wid * 16 + (lane >> 4) * 4 + r;
            if (n <= 1024)
                ob[(size_t)(b * N_ + n) * C_ + h * D_ + ct * 16 + (lane & 15)] =
                    f2bf(of[ct][r] / lsum[r]);
        }
}

extern "C" void kernel_launch(void* const* d_in, const int* in_sizes, int n_in,
                              void* d_out, int out_size, void* d_ws, size_t ws_size,
                              hipStream_t stream)
{
    const float* x       = (const float*)d_in[0];
    const float* style_k = (const float*)d_in[1];
    const float* style_v = (const float*)d_in[2];
    const float* W_qkv   = (const float*)d_in[3];
    const float* W_proj  = (const float*)d_in[4];
    const float* b_proj  = (const float*)d_in[5];
    const float* ak      = (const float*)d_in[6];
    const float* bk      = (const float*)d_in[7];
    const float* av      = (const float*)d_in[8];
    const float* bv      = (const float*)d_in[9];
    const float* W1      = (const float*)d_in[10];
    const float* b1      = (const float*)d_in[11];
    const float* W2      = (const float*)d_in[12];
    const float* b2      = (const float*)d_in[13];

    float* outp   = (float*)d_out;
    float* vv_out = outp + (size_t)M_ * C_;        // second tuple output (fp32)

    // scratch parked in d_out x_return region (dead until proj_gemm writes it):
    u16* WqkvT = (u16*)outp;                       // 3072*1024
    u16* Tk    = WqkvT + (size_t)3072 * 1024;      // 1024*1024
    u16* Tv    = Tk + (size_t)1024 * 1024;         // 1024*1024
    u16* xbb   = Tv + (size_t)1024 * 1024;         // M_*C_ bf16 (ends at 27.3MB < 33.6MB)

    // ws layout (u16 units): ~69.4 MB
    u16* ws     = (u16*)d_ws;
    u16* qb     = ws;                              // M_*C_
    u16* kkb    = qb  + (size_t)M_ * C_;           // M_*C_
    u16* obuf   = kkb + (size_t)M_ * C_;           // M_*C_  (aliases skb during qkv)
    u16* vvT    = obuf + (size_t)M_ * C_;          // 64*128*NPAD_ (aliases svb during qkv)
    u16* WprojT = vvT + (size_t)B_ * H_ * D_ * NPAD_;
    float* wcls = (float*)(WprojT + (size_t)1024 * 1024);
    u16* skb = obuf;   // lifetime: cast3 .. qkv   (attn writes obuf later)
    u16* svb = vvT;    // lifetime: cast3 .. qkv   (vvt writes vvT later)

    wt_kernel<<<dim3(96, 32), 256, 0, stream>>>(W_qkv, WqkvT, 1024, 3072);
    wt_kernel<<<dim3(32, 32), 256, 0, stream>>>(W_proj, WprojT, 1024, 1024);
    tokens_kernel<<<dim3(4, 1024, 2), 256, 0, stream>>>(ak, bk, av, bv, Tk, Tv);
    cast3_kernel<<<dim3(4100, 3), 256, 0, stream>>>(x, style_k, style_v, xbb, skb, svb);
    se_kernel<<<dim3(B_ * (C_ / 8)), 256, 0, stream>>>(x, W1, b1, W2, b2, wcls);

    qkv_gemm<<<dim3(65 * 24), 256, 0, stream>>>(xbb, skb, svb, WqkvT, Tk, Tv,
                                                qb, kkb, vv_out);
    vvt_kernel<<<dim3(33, 4, 64), 256, 0, stream>>>(vv_out, vvT);
    attn_kernel<<<dim3(17 * 64), 256, 0, stream>>>(qb, kkb, vvT, obuf);
    proj_gemm<<<dim3(65 * 8), 256, 0, stream>>>(obuf, WprojT, b_proj, wcls, outp);
}

// Round 6
// 400.766 us; speedup vs baseline: 12.1333x; 1.1612x over previous
//
#include <hip/hip_runtime.h>
#include <hip/hip_bf16.h>
#include <stdint.h>

#define B_ 8
#define N_ 1025
#define C_ 1024
#define H_ 8
#define D_ 128
#define TOK_ 1024
#define LORA_ 16
#define M_ 8200          // B_*N_
#define NPAD_ 1032       // padded N for vvT rows

using bf16x8 = __attribute__((ext_vector_type(8))) short;
using f32x4  = __attribute__((ext_vector_type(4))) float;
typedef unsigned short u16;

__device__ __forceinline__ u16 f2bf(float f) {
    union { float f; unsigned u; } v; v.f = f;
    unsigned r = v.u + 0x7fffu + ((v.u >> 16) & 1u);   // RNE
    return (u16)(r >> 16);
}

__device__ __forceinline__ void gload16(const u16* g, u16* l) {
    __builtin_amdgcn_global_load_lds(
        (const __attribute__((address_space(1))) void*)g,
        (__attribute__((address_space(3))) void*)l, 16, 0, 0);
}

// bijective XCD swizzle (nwg % 8 == 0)
__device__ __forceinline__ int xcd_swz(int bid, int nwg) {
    int cpx = nwg >> 3;
    return (bid & 7) * cpx + (bid >> 3);
}

// ---------------- fp32 -> bf16 cast (x, style_k, style_v), 8 elems/thread --------------
__global__ __launch_bounds__(256) void cast3_kernel(
    const float* __restrict__ x, const float* __restrict__ sk, const float* __restrict__ sv,
    u16* __restrict__ xb, u16* __restrict__ skb, u16* __restrict__ svb)
{
    const float* in = blockIdx.y == 0 ? x : (blockIdx.y == 1 ? sk : sv);
    u16* out = blockIdx.y == 0 ? xb : (blockIdx.y == 1 ? skb : svb);
    size_t i = (size_t)blockIdx.x * 256 + threadIdx.x;   // covers M_*C_/8 exactly
    float4 a = *((const float4*)in + i * 2);
    float4 b = *((const float4*)in + i * 2 + 1);
    bf16x8 v;
    v[0] = (short)f2bf(a.x); v[1] = (short)f2bf(a.y);
    v[2] = (short)f2bf(a.z); v[3] = (short)f2bf(a.w);
    v[4] = (short)f2bf(b.x); v[5] = (short)f2bf(b.y);
    v[6] = (short)f2bf(b.z); v[7] = (short)f2bf(b.w);
    *(bf16x8*)(out + i * 8) = v;
}

// ---------------- tokens: Tk[t][c] = sum_l ak[t,l]*bk[l,c]  (bf16 B^T layout) ----------
__global__ __launch_bounds__(256) void tokens_kernel(
    const float* __restrict__ ak, const float* __restrict__ bk,
    const float* __restrict__ av, const float* __restrict__ bv,
    u16* __restrict__ Tk, u16* __restrict__ Tv)
{
    const float* a = blockIdx.z ? av : ak;
    const float* b = blockIdx.z ? bv : bk;
    u16* o = blockIdx.z ? Tv : Tk;
    int c = blockIdx.x * 256 + threadIdx.x;
    int t = blockIdx.y;
    float s = 0.f;
#pragma unroll
    for (int l = 0; l < LORA_; ++l) s += a[t * LORA_ + l] * b[l * C_ + c];
    o[(size_t)t * C_ + c] = f2bf(s);
}

// ---------------- weight transpose+cast: in (K x Nw) f32 -> out (Nw x K) bf16 ----------
__global__ __launch_bounds__(256) void wt_kernel(
    const float* __restrict__ in, u16* __restrict__ out, int K, int Nw)
{
    __shared__ float t[32][33];
    int n0 = blockIdx.x * 32, k0 = blockIdx.y * 32;
    int tx = threadIdx.x & 31, ty = threadIdx.x >> 5;
#pragma unroll
    for (int yy = 0; yy < 32; yy += 8)
        t[ty + yy][tx] = in[(size_t)(k0 + ty + yy) * Nw + n0 + tx];
    __syncthreads();
#pragma unroll
    for (int yy = 0; yy < 32; yy += 8)
        out[(size_t)(n0 + ty + yy) * K + k0 + tx] = f2bf(t[tx][ty + yy]);
}

// ---------------- x[b,1+t,c] f32 -> xT bf16 [b*1024+c][t] ------------------------------
__global__ __launch_bounds__(256) void xt_kernel(
    const float* __restrict__ x, u16* __restrict__ xT)
{
    __shared__ float tb[32][33];
    int t0 = blockIdx.x * 32, c0 = blockIdx.y * 32, b = blockIdx.z;
    int tx = threadIdx.x & 31, ty = threadIdx.x >> 5;
#pragma unroll
    for (int yy = 0; yy < 32; yy += 8)
        tb[ty + yy][tx] = x[((size_t)b * N_ + 1 + t0 + ty + yy) * C_ + c0 + tx];
    __syncthreads();
#pragma unroll
    for (int yy = 0; yy < 32; yy += 8)
        xT[((size_t)b * 1024 + c0 + ty + yy) * 1024 + t0 + tx] = f2bf(tb[tx][ty + yy]);
}

// ---------------- vv (f32) -> vvT bf16 [bh*128+d][NPAD_] -------------------------------
__global__ __launch_bounds__(256) void vvt_kernel(
    const float* __restrict__ vv, u16* __restrict__ vvT)
{
    __shared__ float t[32][33];
    int n0 = blockIdx.x * 32, d0 = blockIdx.y * 32, bh = blockIdx.z;
    int b = bh >> 3, h = bh & 7;
    int tx = threadIdx.x & 31, ty = threadIdx.x >> 5;
#pragma unroll
    for (int yy = 0; yy < 32; yy += 8) {
        int n = n0 + ty + yy; if (n > 1024) n = 1024;
        t[ty + yy][tx] = vv[((size_t)(b * N_) + n) * C_ + h * D_ + d0 + tx];
    }
    __syncthreads();
#pragma unroll
    for (int yy = 0; yy < 32; yy += 8) {
        int n = n0 + tx;
        if (n < NPAD_)
            vvT[((size_t)bh * D_ + d0 + ty + yy) * NPAD_ + n] = f2bf(t[tx][ty + yy]);
    }
}

// ---------------- MFMA GEMM core (bf16 A and B, both via global_load_lds) --------------
// Tile 128x128, BK=64. LDS tile rows = 128 B, XOR-swizzle byte^((row&7)<<4).
__device__ __forceinline__ void stage_tile(
    const u16* __restrict__ base, int row0, int maxrow,
    u16* lds, int k0, int lane, int wid)
{
#pragma unroll
    for (int j = 0; j < 4; ++j) {
        int i = wid * 4 + j;
        int p = i * 1024 + 16 * lane;           // linear LDS byte this lane fills
        int row = p >> 7, cb = p & 127;
        int cbs = cb ^ ((row & 7) << 4);        // inverse-swizzled source column
        int gr = row0 + row; if (gr > maxrow) gr = maxrow;
        gload16(base + (size_t)gr * 1024 + k0 + (cbs >> 1), lds + i * 512);
    }
}

__device__ __forceinline__ void gemm_pass(
    const u16* __restrict__ A, const u16* __restrict__ Bt, int row0, int nb0,
    u16* As, u16* Bs, f32x4 acc[4][4],
    const int lane, const int wid, const int wr, const int wc)
{
    for (int k0 = 0; k0 < 1024; k0 += 64) {
        __syncthreads();
        stage_tile(A,  row0, M_ - 1,    As, k0, lane, wid);
        stage_tile(Bt, nb0,  (1 << 30), Bs, k0, lane, wid);
        __syncthreads();
#pragma unroll
        for (int ks = 0; ks < 2; ++ks) {
            bf16x8 af[4], bfr[4];
#pragma unroll
            for (int mi = 0; mi < 4; ++mi) {
                int r = wr * 64 + mi * 16 + (lane & 15);
                int byte = (r * 128 + ks * 64 + (lane >> 4) * 16) ^ ((r & 7) << 4);
                af[mi] = *(const bf16x8*)((const char*)As + byte);
            }
#pragma unroll
            for (int ni = 0; ni < 4; ++ni) {
                int r = wc * 64 + ni * 16 + (lane & 15);
                int byte = (r * 128 + ks * 64 + (lane >> 4) * 16) ^ ((r & 7) << 4);
                bfr[ni] = *(const bf16x8*)((const char*)Bs + byte);
            }
#pragma unroll
            for (int mi = 0; mi < 4; ++mi)
#pragma unroll
                for (int ni = 0; ni < 4; ++ni)
                    acc[mi][ni] = __builtin_amdgcn_mfma_f32_16x16x32_bf16(
                        af[mi], bfr[ni], acc[mi][ni], 0, 0, 0);
        }
    }
}

// ---------------- SE module as MFMA GEMM + fused relu*W2 reduce ------------------------
// H[row=b*1024+c][j] = sum_t xT[row][t]*W1T[j][t]; wcls[row] = x[b,0,c]*sigmoid(sum_j relu(H+b1)*W2 + b2)
__global__ __launch_bounds__(256) void se_gemm(
    const u16* __restrict__ xT, const u16* __restrict__ W1T,
    const float* __restrict__ b1, const float* __restrict__ W2,
    const float* __restrict__ b2, const float* __restrict__ x,
    float* __restrict__ wcls)
{
    __shared__ u16 As[8192], Bs[8192];
    __shared__ float red[128];
    const int tid = threadIdx.x, lane = tid & 63, wid = tid >> 6;
    const int wr = wid >> 1, wc = wid & 1;
    const int row0 = blockIdx.x * 128;
    if (tid < 128) red[tid] = 0.f;
    const f32x4 FZ = {0.f, 0.f, 0.f, 0.f};

#pragma unroll
    for (int pass = 0; pass < 2; ++pass) {
        f32x4 acc[4][4];
#pragma unroll
        for (int mi = 0; mi < 4; ++mi)
#pragma unroll
            for (int ni = 0; ni < 4; ++ni) acc[mi][ni] = FZ;
        gemm_pass(xT, W1T, row0, pass * 128, As, Bs, acc, lane, wid, wr, wc);
#pragma unroll
        for (int mi = 0; mi < 4; ++mi) {
#pragma unroll
            for (int r = 0; r < 4; ++r) {
                float v = 0.f;
#pragma unroll
                for (int ni = 0; ni < 4; ++ni) {
                    int j = pass * 128 + wc * 64 + ni * 16 + (lane & 15);
                    float h = acc[mi][ni][r] + b1[j];
                    v += fmaxf(h, 0.f) * W2[j];
                }
#pragma unroll
                for (int off = 1; off < 16; off <<= 1) v += __shfl_xor(v, off);
                if ((lane & 15) == 0)
                    atomicAdd(&red[wr * 64 + mi * 16 + (lane >> 4) * 4 + r], v);
            }
        }
    }
    __syncthreads();
    if (tid < 128) {
        int row = row0 + tid;                 // = b*1024 + c
        int b = row >> 10, c = row & 1023;
        float aw = 1.f / (1.f + expf(-(red[tid] + b2[0])));
        wcls[row] = x[(size_t)b * N_ * C_ + c] * aw;
    }
}

// ---------------- fused qkv GEMM: regions q / kk(+lora) / vv(+lora) --------------------
__global__ __launch_bounds__(256) void qkv_gemm(
    const u16* __restrict__ xb, const u16* __restrict__ skb, const u16* __restrict__ svb,
    const u16* __restrict__ WqkvT, const u16* __restrict__ Tk, const u16* __restrict__ Tv,
    u16* __restrict__ qb, u16* __restrict__ kkb, float* __restrict__ vvout)
{
    __shared__ u16 As[8192], Bs[8192];
    const int tid = threadIdx.x, lane = tid & 63, wid = tid >> 6;
    const int wr = wid >> 1, wc = wid & 1;
    const int swz = xcd_swz(blockIdx.x, 65 * 24);
    const int row0 = (swz / 24) * 128;          // A-locality: ct fastest
    const int ct = swz % 24, region = ct >> 3;
    const f32x4 FZ = {0.f, 0.f, 0.f, 0.f};
    f32x4 acc[4][4];
#pragma unroll
    for (int mi = 0; mi < 4; ++mi)
#pragma unroll
        for (int ni = 0; ni < 4; ++ni) acc[mi][ni] = FZ;

    gemm_pass(xb, WqkvT, row0, ct * 128, As, Bs, acc, lane, wid, wr, wc);
    if (region == 1) gemm_pass(skb, Tk, row0, (ct & 7) * 128, As, Bs, acc, lane, wid, wr, wc);
    if (region == 2) gemm_pass(svb, Tv, row0, (ct & 7) * 128, As, Bs, acc, lane, wid, wr, wc);

    const int creg = (ct & 7) * 128;
#pragma unroll
    for (int mi = 0; mi < 4; ++mi) {
#pragma unroll
        for (int r = 0; r < 4; ++r) {
            int gr = row0 + wr * 64 + mi * 16 + (lane >> 4) * 4 + r;
            if (gr >= M_) continue;
#pragma unroll
            for (int ni = 0; ni < 4; ++ni) {
                int gc = creg + wc * 64 + ni * 16 + (lane & 15);
                float v = acc[mi][ni][r];
                if (region == 0)      qb [(size_t)gr * C_ + gc] = f2bf(v);
                else if (region == 1) kkb[(size_t)gr * C_ + gc] = f2bf(v);
                else                  vvout[(size_t)gr * C_ + gc] = v;
            }
        }
    }
}

// ---------------- proj GEMM: out = ob @ WprojT^T + b_proj (+wcls on cls rows) ----------
__global__ __launch_bounds__(256) void proj_gemm(
    const u16* __restrict__ ob, const u16* __restrict__ WprojT,
    const float* __restrict__ bias, const float* __restrict__ wcls,
    float* __restrict__ outp)
{
    __shared__ u16 As[8192], Bs[8192];
    const int tid = threadIdx.x, lane = tid & 63, wid = tid >> 6;
    const int wr = wid >> 1, wc = wid & 1;
    const int swz = xcd_swz(blockIdx.x, 65 * 8);
    const int row0 = (swz / 8) * 128;           // A-locality: ct fastest
    const int ct = swz % 8;
    const f32x4 FZ = {0.f, 0.f, 0.f, 0.f};
    f32x4 acc[4][4];
#pragma unroll
    for (int mi = 0; mi < 4; ++mi)
#pragma unroll
        for (int ni = 0; ni < 4; ++ni) acc[mi][ni] = FZ;

    gemm_pass(ob, WprojT, row0, ct * 128, As, Bs, acc, lane, wid, wr, wc);

#pragma unroll
    for (int mi = 0; mi < 4; ++mi) {
#pragma unroll
        for (int r = 0; r < 4; ++r) {
            int gr = row0 + wr * 64 + mi * 16 + (lane >> 4) * 4 + r;
            if (gr >= M_) continue;
#pragma unroll
            for (int ni = 0; ni < 4; ++ni) {
                int gc = ct * 128 + wc * 64 + ni * 16 + (lane & 15);
                float v = acc[mi][ni][r] + bias[gc];
                if (gr % N_ == 0) v += wcls[(gr / N_) * C_ + gc];
                outp[(size_t)gr * C_ + gc] = v;
            }
        }
    }
}

// ---------------- flash attention, bf16 MFMA, double-buffered K/V prefetch -------------
__device__ __forceinline__ void attn_stage(
    const u16* __restrict__ kbase, const u16* __restrict__ vbase,
    u16* Ksb, u16* Vsb, int kv0, int lane, int wid)
{
#pragma unroll
    for (int j = 0; j < 4; ++j) {
        int i = wid * 4 + j;
        int p = i * 1024 + 16 * lane;
        int row = p >> 8, cb = p & 255;
        int cbs = cb ^ ((row & 7) << 4);
        int n = kv0 + row; if (n > 1024) n = 1024;
        gload16(kbase + (size_t)n * C_ + (cbs >> 1), Ksb + i * 512);
    }
#pragma unroll
    for (int j = 0; j < 4; ++j) {
        int i = wid * 4 + j;
        int p = i * 1024 + 16 * lane;
        int row = p >> 7, cb = p & 127;
        int cbs = cb ^ ((row & 7) << 4);
        int st = kv0 + (cbs >> 1); if (st > NPAD_ - 8) st = NPAD_ - 8;
        gload16(vbase + (size_t)row * NPAD_ + st, Vsb + i * 512);
    }
}

__global__ __launch_bounds__(256) void attn_kernel(
    const u16* __restrict__ qb, const u16* __restrict__ kkb,
    const u16* __restrict__ vvT, u16* __restrict__ ob)
{
    __shared__ u16 Ks[2][8192];   // [64 kv][128 d], swizzled, dbuf
    __shared__ u16 Vs[2][8192];   // [128 d][64 kv], swizzled, dbuf
    __shared__ u16 Ps[4096];      // per-wave [16 q][64 kv], swizzled
    const int tid = threadIdx.x, lane = tid & 63, wid = tid >> 6;
    const int swz = xcd_swz(blockIdx.x, 17 * 64);
    const int qt = swz % 17, bh = swz / 17, b = bh >> 3, h = bh & 7;
    const int n0q = qt * 64;
    const float SCALE = 0.08838834764831845f;
    const u16* kbase = kkb + (size_t)b * N_ * C_ + h * D_;
    const u16* vbase = vvT + (size_t)bh * D_ * NPAD_;

    bf16x8 qf[4];
    {
        int qrow = n0q + wid * 16 + (lane & 15); if (qrow > 1024) qrow = 1024;
        const u16* qbase = qb + (size_t)(b * N_ + qrow) * C_ + h * D_ + (lane >> 4) * 8;
#pragma unroll
        for (int ks = 0; ks < 4; ++ks) qf[ks] = *(const bf16x8*)(qbase + ks * 32);
    }

    float mrow[4], lsum[4];
    const f32x4 FZ = {0.f, 0.f, 0.f, 0.f};
    f32x4 of[8];
#pragma unroll
    for (int r = 0; r < 4; ++r) { mrow[r] = -3e38f; lsum[r] = 0.f; }
#pragma unroll
    for (int ct = 0; ct < 8; ++ct) of[ct] = FZ;

    char* psb = (char*)Ps + wid * 2048;

    attn_stage(kbase, vbase, Ks[0], Vs[0], 0, lane, wid);

    for (int t = 0; t < 17; ++t) {
        const int cur = t & 1;
        const int kv0 = t * 64;
        __syncthreads();   // drains this wave's vmcnt -> buf[cur] ready; prev reads of buf[cur^1] done
        if (t < 16)
            attn_stage(kbase, vbase, Ks[cur ^ 1], Vs[cur ^ 1], (t + 1) * 64, lane, wid);

        f32x4 s[4];
        __builtin_amdgcn_s_setprio(1);
#pragma unroll
        for (int jt = 0; jt < 4; ++jt) {
            f32x4 a = FZ;
#pragma unroll
            for (int ks = 0; ks < 4; ++ks) {
                int kvr = jt * 16 + (lane & 15);
                int byte = (kvr * 256 + ks * 64 + (lane >> 4) * 16) ^ ((kvr & 7) << 4);
                bf16x8 kf = *(const bf16x8*)((const char*)Ks[cur] + byte);
                a = __builtin_amdgcn_mfma_f32_16x16x32_bf16(qf[ks], kf, a, 0, 0, 0);
            }
            s[jt] = a;
        }
        __builtin_amdgcn_s_setprio(0);
#pragma unroll
        for (int jt = 0; jt < 4; ++jt) {
            f32x4 a = s[jt] * SCALE;
            int kvglob = kv0 + jt * 16 + (lane & 15);
            if (kvglob > 1024) { a[0] = -3e38f; a[1] = -3e38f; a[2] = -3e38f; a[3] = -3e38f; }
            s[jt] = a;
        }

        float al[4];
#pragma unroll
        for (int r = 0; r < 4; ++r) {
            float tm = fmaxf(fmaxf(s[0][r], s[1][r]), fmaxf(s[2][r], s[3][r]));
#pragma unroll
            for (int off = 1; off < 16; off <<= 1) tm = fmaxf(tm, __shfl_xor(tm, off));
            float mn = fmaxf(mrow[r], tm);
            al[r] = __expf(mrow[r] - mn);
            mrow[r] = mn;
            float ps = 0.f;
#pragma unroll
            for (int jt = 0; jt < 4; ++jt) {
                float p = __expf(s[jt][r] - mn);
                s[jt][r] = p; ps += p;
            }
#pragma unroll
            for (int off = 1; off < 16; off <<= 1) ps += __shfl_xor(ps, off);
            lsum[r] = lsum[r] * al[r] + ps;
        }

#pragma unroll
        for (int jt = 0; jt < 4; ++jt)
#pragma unroll
            for (int r = 0; r < 4; ++r) {
                int pr = (lane >> 4) * 4 + r;
                int byte = (pr * 128 + (jt * 16 + (lane & 15)) * 2) ^ ((pr & 7) << 4);
                *(u16*)(psb + byte) = f2bf(s[jt][r]);
            }
#pragma unroll
        for (int ct = 0; ct < 8; ++ct)
#pragma unroll
            for (int r = 0; r < 4; ++r) of[ct][r] *= al[r];

        bf16x8 pa[2];
#pragma unroll
        for (int ks2 = 0; ks2 < 2; ++ks2) {
            int prr = lane & 15;
            int byte = (prr * 128 + ks2 * 64 + (lane >> 4) * 16) ^ ((prr & 7) << 4);
            pa[ks2] = *(const bf16x8*)(psb + byte);
        }
        __builtin_amdgcn_s_setprio(1);
#pragma unroll
        for (int ct = 0; ct < 8; ++ct)
#pragma unroll
            for (int ks2 = 0; ks2 < 2; ++ks2) {
                int d = ct * 16 + (lane & 15);
                int byte = (d * 128 + ks2 * 64 + (lane >> 4) * 16) ^ ((d & 7) << 4);
                bf16x8 vf = *(const bf16x8*)((const char*)Vs[cur] + byte);
                of[ct] = __builtin_amdgcn_mfma_f32_16x16x32_bf16(pa[ks2], vf, of[ct], 0, 0, 0);
            }
        __builtin_amdgcn_s_setprio(0);
    }

#pragma unroll
    for (int ct = 0; ct < 8; ++ct)
#pragma unroll
        for (int r = 0; r < 4; ++r) {
            int n = n0q + wid * 16 + (lane >> 4) * 4 + r;
            if (n <= 1024)
                ob[(size_t)(b * N_ + n) * C_ + h * D_ + ct * 16 + (lane & 15)] =
                    f2bf(of[ct][r] / lsum[r]);
        }
}

extern "C" void kernel_launch(void* const* d_in, const int* in_sizes, int n_in,
                              void* d_out, int out_size, void* d_ws, size_t ws_size,
                              hipStream_t stream)
{
    const float* x       = (const float*)d_in[0];
    const float* style_k = (const float*)d_in[1];
    const float* style_v = (const float*)d_in[2];
    const float* W_qkv   = (const float*)d_in[3];
    const float* W_proj  = (const float*)d_in[4];
    const float* b_proj  = (const float*)d_in[5];
    const float* ak      = (const float*)d_in[6];
    const float* bk      = (const float*)d_in[7];
    const float* av      = (const float*)d_in[8];
    const float* bv      = (const float*)d_in[9];
    const float* W1      = (const float*)d_in[10];
    const float* b1      = (const float*)d_in[11];
    const float* W2      = (const float*)d_in[12];
    const float* b2      = (const float*)d_in[13];

    float* outp   = (float*)d_out;
    float* vv_out = outp + (size_t)M_ * C_;        // second tuple output (fp32)

    // scratch parked in d_out x_return region (dead until proj_gemm writes it):
    u16* WqkvT = (u16*)outp;                       // 3072*1024
    u16* Tk    = WqkvT + (size_t)3072 * 1024;      // 1024*1024
    u16* Tv    = Tk + (size_t)1024 * 1024;         // 1024*1024
    u16* xbb   = Tv + (size_t)1024 * 1024;         // M_*C_
    u16* W1T   = xbb + (size_t)M_ * C_;            // 256*1024 (ends ~27.8MB < 33.6MB)

    // ws layout (u16 units): ~69.4 MB
    u16* ws     = (u16*)d_ws;
    u16* qb     = ws;                              // M_*C_   (xT alias before qkv)
    u16* kkb    = qb  + (size_t)M_ * C_;           // M_*C_
    u16* obuf   = kkb + (size_t)M_ * C_;           // M_*C_   (skb alias before qkv)
    u16* vvT    = obuf + (size_t)M_ * C_;          // 64*128*NPAD_ (svb alias before qkv)
    u16* WprojT = vvT + (size_t)B_ * H_ * D_ * NPAD_;
    float* wcls = (float*)(WprojT + (size_t)1024 * 1024);
    u16* skb = obuf;   // lifetime: cast3 .. qkv
    u16* svb = vvT;    // lifetime: cast3 .. qkv
    u16* xT  = qb;     // lifetime: xt .. se_gemm (qkv overwrites after)

    wt_kernel<<<dim3(96, 32), 256, 0, stream>>>(W_qkv, WqkvT, 1024, 3072);
    wt_kernel<<<dim3(32, 32), 256, 0, stream>>>(W_proj, WprojT, 1024, 1024);
    wt_kernel<<<dim3(8, 32), 256, 0, stream>>>(W1, W1T, 1024, 256);
    tokens_kernel<<<dim3(4, 1024, 2), 256, 0, stream>>>(ak, bk, av, bv, Tk, Tv);
    cast3_kernel<<<dim3(4100, 3), 256, 0, stream>>>(x, style_k, style_v, xbb, skb, svb);
    xt_kernel<<<dim3(32, 32, 8), 256, 0, stream>>>(x, xT);
    se_gemm<<<dim3(64), 256, 0, stream>>>(xT, W1T, b1, W2, b2, x, wcls);

    qkv_gemm<<<dim3(65 * 24), 256, 0, stream>>>(xbb, skb, svb, WqkvT, Tk, Tv,
                                                qb, kkb, vv_out);
    vvt_kernel<<<dim3(33, 4, 64), 256, 0, stream>>>(vv_out, vvT);
    attn_kernel<<<dim3(17 * 64), 256, 0, stream>>>(qb, kkb, vvT, obuf);
    proj_gemm<<<dim3(65 * 8), 256, 0, stream>>>(obuf, WprojT, b_proj, wcls, outp);
}